// Round 6
// baseline (602.991 us; speedup 1.0000x reference)
//
#include <hip/hip_runtime.h>
#include <math.h>

#define D 128

typedef unsigned int u32;

__device__ __forceinline__ u32 rotl32(u32 x, int r){ return (x<<r) | (x>>(32-r)); }

// eps = jax.random.normal(jax.random.key(42), ...), element m (row-major flat).
// JAX threefry PARTITIONABLE layout: counter (hi,lo)=(0,m), key=(0,42);
// 32-bit output = x0_final ^ x1_final. Then uniform in [-1+2^-24, 1) and
// sqrt(2)*erfinv (XLA Giles polynomial).  [verified bit-correct in R3]
__device__ __forceinline__ float jax_normal_part_xor(u32 m){
  const u32 ks0 = 0u, ks1 = 42u, ks2 = 0x1BD11BF0u; // 0x1BD11BDA ^ 0 ^ 42
  u32 x0 = 0u + ks0;
  u32 x1 = m  + ks1;
  #define TF_R4(a,b,c,d) \
    x0 += x1; x1 = rotl32(x1,(a)); x1 ^= x0; \
    x0 += x1; x1 = rotl32(x1,(b)); x1 ^= x0; \
    x0 += x1; x1 = rotl32(x1,(c)); x1 ^= x0; \
    x0 += x1; x1 = rotl32(x1,(d)); x1 ^= x0;
  TF_R4(13,15,26,6)   x0 += ks1; x1 += ks2 + 1u;
  TF_R4(17,29,16,24)  x0 += ks2; x1 += ks0 + 2u;
  TF_R4(13,15,26,6)   x0 += ks0; x1 += ks1 + 3u;
  TF_R4(17,29,16,24)  x0 += ks1; x1 += ks2 + 4u;
  TF_R4(13,15,26,6)   x0 += ks2; x1 += ks0 + 5u;
  #undef TF_R4
  u32 bits = x0 ^ x1;
  float f = __uint_as_float((bits >> 9) | 0x3F800000u) - 1.0f;   // [0,1)
  const float LO = -0.99999994f;                                  // nextafter(-1,0)
  float u = fmaxf(LO, f * 2.0f + LO);
  float w = -log1pf(-u*u);
  float p;
  if (w < 5.0f){
    w -= 2.5f;
    p =  2.81022636e-08f;
    p = fmaf(p, w,  3.43273939e-07f);
    p = fmaf(p, w, -3.5233877e-06f);
    p = fmaf(p, w, -4.39150654e-06f);
    p = fmaf(p, w,  0.00021858087f);
    p = fmaf(p, w, -0.00125372503f);
    p = fmaf(p, w, -0.00417768164f);
    p = fmaf(p, w,  0.246640727f);
    p = fmaf(p, w,  1.50140941f);
  } else {
    w = sqrtf(w) - 3.0f;
    p = -0.000200214257f;
    p = fmaf(p, w,  0.000100950558f);
    p = fmaf(p, w,  0.00134934322f);
    p = fmaf(p, w, -0.00367342844f);
    p = fmaf(p, w,  0.00573950773f);
    p = fmaf(p, w, -0.0076224613f);
    p = fmaf(p, w,  0.00943887047f);
    p = fmaf(p, w,  1.00167406f);
    p = fmaf(p, w,  2.83297682f);
  }
  return 1.41421354f * (p * u);
}

__device__ __forceinline__ float sigmoidf_(float z){ return 1.0f / (1.0f + __expf(-z)); }

// ---------------- index normalization (int32 vs int64 edge_index) ----------------
__global__ void k_detect(const u32* __restrict__ e_u32, int* __restrict__ flag){
  __shared__ int s_nz;
  if (threadIdx.x == 0) s_nz = 0;
  __syncthreads();
  if (e_u32[2*threadIdx.x + 1] != 0u) atomicAdd(&s_nz, 1);
  __syncthreads();
  if (threadIdx.x == 0) *flag = (s_nz == 0) ? 1 : 0;   // all-hi-words-zero => int64
}

__global__ void k_norm(const void* __restrict__ eidx, const int* __restrict__ flag,
                       int* __restrict__ src_w, int* __restrict__ dst_w, int e){
  int i = blockIdx.x*256 + threadIdx.x;
  if (i >= e) return;
  if (*flag){
    const u32* u = (const u32*)eidx;
    src_w[i] = (int)u[2*(size_t)i];
    dst_w[i] = (int)u[2*((size_t)e + i)];
  } else {
    const int* p = (const int*)eidx;
    src_w[i] = p[i];
    dst_w[i] = p[e + i];
  }
}

// ---------------- degree / CSR build (int atomics only — native) ----------------
__global__ void k_init(int* __restrict__ cnt, int n){
  int i = blockIdx.x*256 + threadIdx.x;
  if (i < n) cnt[i] = 0;
}

__global__ void k_hist(const int* __restrict__ dst, int* __restrict__ cnt, int e){
  int i = blockIdx.x*256 + threadIdx.x;
  if (i >= e) return;
  atomicAdd(&cnt[dst[i]], 1);
}

__global__ __launch_bounds__(256) void k_scan1(const int* __restrict__ cnt,
                                               int* __restrict__ rp,
                                               int* __restrict__ bsum, int n){
  __shared__ int sh[256];
  int tid = threadIdx.x, idx = blockIdx.x*256 + tid;
  int v = (idx < n) ? cnt[idx] : 0;
  sh[tid] = v; __syncthreads();
  for (int off = 1; off < 256; off <<= 1){
    int t = (tid >= off) ? sh[tid-off] : 0;
    __syncthreads(); sh[tid] += t; __syncthreads();
  }
  if (idx < n) rp[idx] = sh[tid] - v;     // exclusive within chunk
  if (tid == 255) bsum[blockIdx.x] = sh[255];
}

__global__ __launch_bounds__(1024) void k_scan2(int* __restrict__ bsum, int nb){
  __shared__ int sh[1024];
  int tid = threadIdx.x;
  int v = (tid < nb) ? bsum[tid] : 0;
  sh[tid] = v; __syncthreads();
  for (int off = 1; off < 1024; off <<= 1){
    int t = (tid >= off) ? sh[tid-off] : 0;
    __syncthreads(); sh[tid] += t; __syncthreads();
  }
  if (tid < nb) bsum[tid] = sh[tid] - v;  // exclusive block offsets
}

__global__ void k_scan3(int* __restrict__ rp, int* __restrict__ cur,
                        const int* __restrict__ bsum, const int* __restrict__ cnt,
                        float* __restrict__ dinv_o, int n, int e){
  int idx = blockIdx.x*256 + threadIdx.x;
  if (idx < n){
    int r = rp[idx] + bsum[blockIdx.x];
    rp[idx] = r; cur[idx] = r;
    dinv_o[idx] = rsqrtf((float)(cnt[idx] + 1));
  }
  if (idx == 0) rp[n] = e;
}

__global__ void k_scatter(const int* __restrict__ src, const int* __restrict__ dst,
                          const float* __restrict__ sc, int* __restrict__ cur,
                          int* __restrict__ col, float* __restrict__ wsrt, int e){
  int i = blockIdx.x*256 + threadIdx.x;
  if (i >= e) return;
  int d = dst[i];
  int p = atomicAdd(&cur[d], 1);
  col[p] = src[i];
  wsrt[p] = sc[i];
}

// score-degree per node: 1 (self-loop) + sum of this row's edge weights. No FP atomics.
__global__ void k_deg(const int* __restrict__ rp, const float* __restrict__ wsrt,
                      float* __restrict__ dinv_s, int n){
  int i = blockIdx.x*256 + threadIdx.x;
  if (i >= n) return;
  float s = 1.0f;
  int e0 = rp[i], e1 = rp[i+1];
  for (int j = e0; j < e1; ++j) s += wsrt[j];
  dinv_s[i] = rsqrtf(s);
}

// ---------------- aggregations: one wave per node ----------------
__global__ __launch_bounds__(256) void k_agg_dual(
    const float* __restrict__ x, const int* __restrict__ rp,
    const int* __restrict__ col, const float* __restrict__ wsrt,
    const float* __restrict__ dinv_s, const float* __restrict__ dinv_o,
    float* __restrict__ out_s, float* __restrict__ out_o, int n){
  int wid = (blockIdx.x * 256 + threadIdx.x) >> 6;
  int lane = threadIdx.x & 63;
  if (wid >= n) return;
  const float2* x2 = (const float2*)x;
  float dsv = dinv_s[wid], dov = dinv_o[wid];
  float2 xv = x2[(size_t)wid*64 + lane];
  float ss = dsv*dsv, oo = dov*dov;                      // self-loop (w=1)
  float2 as = { xv.x*ss, xv.y*ss };
  float2 ao = { xv.x*oo, xv.y*oo };
  int e0 = rp[wid], e1 = rp[wid+1];
  for (int base = e0; base < e1; base += 64){
    int cnt = e1 - base; if (cnt > 64) cnt = 64;
    int idx = base + (lane < cnt ? lane : cnt - 1);
    int   sl = col[idx];
    float wl = wsrt[idx];
    float nsl = dinv_s[sl] * wl * dsv;
    float nol = dinv_o[sl] * dov;
    int j = 0;
    for (; j + 4 <= cnt; j += 4){
      int   s0=__shfl(sl,j),   s1=__shfl(sl,j+1),   s2=__shfl(sl,j+2),   s3=__shfl(sl,j+3);
      float a0=__shfl(nsl,j),  a1=__shfl(nsl,j+1),  a2=__shfl(nsl,j+2),  a3=__shfl(nsl,j+3);
      float b0=__shfl(nol,j),  b1=__shfl(nol,j+1),  b2=__shfl(nol,j+2),  b3=__shfl(nol,j+3);
      float2 r0 = x2[(size_t)s0*64 + lane];
      float2 r1 = x2[(size_t)s1*64 + lane];
      float2 r2 = x2[(size_t)s2*64 + lane];
      float2 r3 = x2[(size_t)s3*64 + lane];
      as.x = fmaf(a0,r0.x,as.x); as.y = fmaf(a0,r0.y,as.y);
      ao.x = fmaf(b0,r0.x,ao.x); ao.y = fmaf(b0,r0.y,ao.y);
      as.x = fmaf(a1,r1.x,as.x); as.y = fmaf(a1,r1.y,as.y);
      ao.x = fmaf(b1,r1.x,ao.x); ao.y = fmaf(b1,r1.y,ao.y);
      as.x = fmaf(a2,r2.x,as.x); as.y = fmaf(a2,r2.y,as.y);
      ao.x = fmaf(b2,r2.x,ao.x); ao.y = fmaf(b2,r2.y,ao.y);
      as.x = fmaf(a3,r3.x,as.x); as.y = fmaf(a3,r3.y,as.y);
      ao.x = fmaf(b3,r3.x,ao.x); ao.y = fmaf(b3,r3.y,ao.y);
    }
    for (; j < cnt; ++j){
      int   s0=__shfl(sl,j);
      float a0=__shfl(nsl,j), b0=__shfl(nol,j);
      float2 r0 = x2[(size_t)s0*64 + lane];
      as.x = fmaf(a0,r0.x,as.x); as.y = fmaf(a0,r0.y,as.y);
      ao.x = fmaf(b0,r0.x,ao.x); ao.y = fmaf(b0,r0.y,ao.y);
    }
  }
  ((float2*)out_s)[(size_t)wid*64 + lane] = as;
  ((float2*)out_o)[(size_t)wid*64 + lane] = ao;
}

__global__ __launch_bounds__(256) void k_agg_one(
    const float* __restrict__ h, const int* __restrict__ rp,
    const int* __restrict__ col, const float* __restrict__ dinv_o,
    float* __restrict__ out, int n){
  int wid = (blockIdx.x * 256 + threadIdx.x) >> 6;
  int lane = threadIdx.x & 63;
  if (wid >= n) return;
  const float2* h2 = (const float2*)h;
  float dov = dinv_o[wid];
  float2 hv = h2[(size_t)wid*64 + lane];
  float oo = dov*dov;
  float2 ao = { hv.x*oo, hv.y*oo };
  int e0 = rp[wid], e1 = rp[wid+1];
  for (int base = e0; base < e1; base += 64){
    int cnt = e1 - base; if (cnt > 64) cnt = 64;
    int idx = base + (lane < cnt ? lane : cnt - 1);
    int   sl = col[idx];
    float nol = dinv_o[sl] * dov;
    int j = 0;
    for (; j + 4 <= cnt; j += 4){
      int   s0=__shfl(sl,j),  s1=__shfl(sl,j+1),  s2=__shfl(sl,j+2),  s3=__shfl(sl,j+3);
      float b0=__shfl(nol,j), b1=__shfl(nol,j+1), b2=__shfl(nol,j+2), b3=__shfl(nol,j+3);
      float2 r0 = h2[(size_t)s0*64 + lane];
      float2 r1 = h2[(size_t)s1*64 + lane];
      float2 r2 = h2[(size_t)s2*64 + lane];
      float2 r3 = h2[(size_t)s3*64 + lane];
      ao.x = fmaf(b0,r0.x,ao.x); ao.y = fmaf(b0,r0.y,ao.y);
      ao.x = fmaf(b1,r1.x,ao.x); ao.y = fmaf(b1,r1.y,ao.y);
      ao.x = fmaf(b2,r2.x,ao.x); ao.y = fmaf(b2,r2.y,ao.y);
      ao.x = fmaf(b3,r3.x,ao.x); ao.y = fmaf(b3,r3.y,ao.y);
    }
    for (; j < cnt; ++j){
      int   s0=__shfl(sl,j);
      float b0=__shfl(nol,j);
      float2 r0 = h2[(size_t)s0*64 + lane];
      ao.x = fmaf(b0,r0.x,ao.x); ao.y = fmaf(b0,r0.y,ao.y);
    }
  }
  ((float2*)out)[(size_t)wid*64 + lane] = ao;
}

// ---------------- GEMMs: 32-row tile, W staged in LDS K-chunks of 32 ------------
// A-tile 16KB + W-chunks in LDS; next chunk register-prefetched so global-load
// latency hides under the current chunk's FMAs. ds_read replaces the per-wave
// L2-latency-bound W stream (R5 diagnosis: waves 85% stalled on W loads).
#define FMA4(accr, a, w0,w1,w2,w3) \
  accr[0] = fmaf(a.x,w0.x, fmaf(a.y,w1.x, fmaf(a.z,w2.x, fmaf(a.w,w3.x, accr[0])))); \
  accr[1] = fmaf(a.x,w0.y, fmaf(a.y,w1.y, fmaf(a.z,w2.y, fmaf(a.w,w3.y, accr[1])))); \
  accr[2] = fmaf(a.x,w0.z, fmaf(a.y,w1.z, fmaf(a.z,w2.z, fmaf(a.w,w3.z, accr[2])))); \
  accr[3] = fmaf(a.x,w0.w, fmaf(a.y,w1.w, fmaf(a.z,w2.w, fmaf(a.w,w3.w, accr[3]))));

#define STAGE_A(Abuf)                                                         \
  _Pragma("unroll")                                                           \
  for (int i = tid; i < 32*32; i += 256){                                     \
    int r = i >> 5, c4 = (i & 31) << 2;                                       \
    float4 v = {0.f,0.f,0.f,0.f};                                             \
    if (row0 + r < n) v = *(const float4*)((Abuf) + (size_t)(row0+r)*D + c4); \
    *(float4*)&As[r][c4] = v;                                                 \
  }

// Dual-W staged main loop -> acc1, acc2 (uses As, Ws1, Ws2; 48 KB LDS)
#define DUAL_MAIN(W1p, W2p)                                                   \
  float4 rA[4], rB[4];                                                        \
  _Pragma("unroll")                                                           \
  for (int j = 0; j < 4; ++j){                                                \
    int i = tid + 256*j; int r = i >> 5, c4 = (i & 31) << 2;                  \
    rA[j] = *(const float4*)((W1p) + (size_t)r*D + c4);                       \
    rB[j] = *(const float4*)((W2p) + (size_t)r*D + c4);                       \
  }                                                                           \
  float acc1[4][4] = {}; float acc2[4][4] = {};                               \
  for (int c = 0; c < 4; ++c){                                                \
    __syncthreads();                                                          \
    _Pragma("unroll")                                                         \
    for (int j = 0; j < 4; ++j){                                              \
      int i = tid + 256*j; int r = i >> 5, c4 = (i & 31) << 2;                \
      *(float4*)&Ws1[r][c4] = rA[j];                                          \
      *(float4*)&Ws2[r][c4] = rB[j];                                          \
    }                                                                         \
    if (c < 3){                                                               \
      _Pragma("unroll")                                                       \
      for (int j = 0; j < 4; ++j){                                            \
        int i = tid + 256*j; int r = (i >> 5) + 32*(c+1), c4 = (i & 31) << 2; \
        rA[j] = *(const float4*)((W1p) + (size_t)r*D + c4);                   \
        rB[j] = *(const float4*)((W2p) + (size_t)r*D + c4);                   \
      }                                                                       \
    }                                                                         \
    __syncthreads();                                                          \
    _Pragma("unroll")                                                         \
    for (int kk = 0; kk < 32; kk += 4){                                       \
      float4 p0 = *(const float4*)&Ws1[kk+0][tx<<2];                          \
      float4 p1 = *(const float4*)&Ws1[kk+1][tx<<2];                          \
      float4 p2 = *(const float4*)&Ws1[kk+2][tx<<2];                          \
      float4 p3 = *(const float4*)&Ws1[kk+3][tx<<2];                          \
      float4 q0 = *(const float4*)&Ws2[kk+0][tx<<2];                          \
      float4 q1 = *(const float4*)&Ws2[kk+1][tx<<2];                          \
      float4 q2 = *(const float4*)&Ws2[kk+2][tx<<2];                          \
      float4 q3 = *(const float4*)&Ws2[kk+3][tx<<2];                          \
      _Pragma("unroll")                                                       \
      for (int r = 0; r < 4; ++r){                                            \
        float4 a = *(const float4*)&As[ty*4+r][32*c+kk];                      \
        FMA4(acc1[r], a, p0,p1,p2,p3)                                         \
        FMA4(acc2[r], a, q0,q1,q2,q3)                                         \
      }                                                                       \
    }                                                                         \
  }

// Two independent act-GEMMs in one launch (blockIdx.y selects slice).
// y=0: out0 = relu(A0@W0 + b0);  y=1: out1 = relu(A1@W1 + b1) + temb[t]
__global__ __launch_bounds__(256) void k_gemm_act2(
    const float* __restrict__ A0, const float* __restrict__ W0, const float* __restrict__ b0,
    const float* __restrict__ A1, const float* __restrict__ W1, const float* __restrict__ b1,
    const float* __restrict__ temb, const int* __restrict__ t_ptr,
    float* __restrict__ out0, float* __restrict__ out1, int n){
  __shared__ float As[32][128];
  __shared__ float Ws1[32][128];
  const int sl = blockIdx.y;
  const float* A = sl ? A1 : A0;
  const float* W = sl ? W1 : W0;
  const float* b = sl ? b1 : b0;
  float* out     = sl ? out1 : out0;
  const int tid = threadIdx.x;
  const int row0 = blockIdx.x * 32;
  STAGE_A(A)
  const int tx = tid & 31, ty = tid >> 5;
  float4 rA[4];
  #pragma unroll
  for (int j = 0; j < 4; ++j){
    int i = tid + 256*j; int r = i >> 5, c4 = (i & 31) << 2;
    rA[j] = *(const float4*)(W + (size_t)r*D + c4);
  }
  float acc[4][4] = {};
  for (int c = 0; c < 4; ++c){
    __syncthreads();
    #pragma unroll
    for (int j = 0; j < 4; ++j){
      int i = tid + 256*j; int r = i >> 5, c4 = (i & 31) << 2;
      *(float4*)&Ws1[r][c4] = rA[j];
    }
    if (c < 3){
      #pragma unroll
      for (int j = 0; j < 4; ++j){
        int i = tid + 256*j; int r = (i >> 5) + 32*(c+1), c4 = (i & 31) << 2;
        rA[j] = *(const float4*)(W + (size_t)r*D + c4);
      }
    }
    __syncthreads();
    #pragma unroll
    for (int kk = 0; kk < 32; kk += 4){
      float4 w0 = *(const float4*)&Ws1[kk+0][tx<<2];
      float4 w1 = *(const float4*)&Ws1[kk+1][tx<<2];
      float4 w2 = *(const float4*)&Ws1[kk+2][tx<<2];
      float4 w3 = *(const float4*)&Ws1[kk+3][tx<<2];
      #pragma unroll
      for (int r = 0; r < 4; ++r){
        float4 a = *(const float4*)&As[ty*4+r][32*c+kk];
        FMA4(acc[r], a, w0,w1,w2,w3)
      }
    }
  }
  float4 bb = ((const float4*)b)[tx];
  float4 tt = {0.f,0.f,0.f,0.f};
  if (sl){ int t = *t_ptr; tt = ((const float4*)temb)[t*32 + tx]; }
  #pragma unroll
  for (int r = 0; r < 4; ++r){
    int row = row0 + ty*4 + r;
    if (row < n){
      float4 o;
      o.x = fmaxf(acc[r][0] + bb.x, 0.f) + tt.x;
      o.y = fmaxf(acc[r][1] + bb.y, 0.f) + tt.y;
      o.z = fmaxf(acc[r][2] + bb.z, 0.f) + tt.z;
      o.w = fmaxf(acc[r][3] + bb.w, 0.f) + tt.w;
      *(float4*)(out + (size_t)row*D + tx*4) = o;
    }
  }
}

// out1 = A@W1 + b1 (linear, prior_mean); out2 = sigmoid(A@W2 + b2) (prior_std)
__global__ __launch_bounds__(256) void k_gemm_dual(
    const float* __restrict__ A,
    const float* __restrict__ W1, const float* __restrict__ b1,
    const float* __restrict__ W2, const float* __restrict__ b2,
    float* __restrict__ out1, float* __restrict__ out2, int n){
  __shared__ float As[32][128];
  __shared__ float Ws1[32][128];
  __shared__ float Ws2[32][128];
  const int tid = threadIdx.x;
  const int row0 = blockIdx.x * 32;
  STAGE_A(A)
  const int tx = tid & 31, ty = tid >> 5;
  DUAL_MAIN(W1, W2)
  float4 bb1 = ((const float4*)b1)[tx];
  float4 bb2 = ((const float4*)b2)[tx];
  #pragma unroll
  for (int r = 0; r < 4; ++r){
    int row = row0 + ty*4 + r;
    if (row < n){
      float4 o1, o2;
      o1.x = acc1[r][0] + bb1.x; o1.y = acc1[r][1] + bb1.y;
      o1.z = acc1[r][2] + bb1.z; o1.w = acc1[r][3] + bb1.w;
      o2.x = sigmoidf_(acc2[r][0] + bb2.x); o2.y = sigmoidf_(acc2[r][1] + bb2.y);
      o2.z = sigmoidf_(acc2[r][2] + bb2.z); o2.w = sigmoidf_(acc2[r][3] + bb2.w);
      *(float4*)(out1 + (size_t)row*D + tx*4) = o1;
      *(float4*)(out2 + (size_t)row*D + tx*4) = o2;
    }
  }
}

// em = A@Wmu + bmu ; es = sigmoid(A@Wstd + bstd); conf = eps*es + em;
// kl partial -> pblk[block] (no global FP atomics).
__global__ __launch_bounds__(256) void k_gemm_final(
    const float* __restrict__ A,
    const float* __restrict__ Wmu, const float* __restrict__ bmu,
    const float* __restrict__ Wstd, const float* __restrict__ bstd,
    const float* __restrict__ pm, const float* __restrict__ ps,
    float* __restrict__ conf, float* __restrict__ pblk, int n){
  __shared__ float As[32][128];
  __shared__ float Ws1[32][128];
  __shared__ float Ws2[32][128];
  const int tid = threadIdx.x;
  const int row0 = blockIdx.x * 32;
  STAGE_A(A)
  const int tx = tid & 31, ty = tid >> 5;
  DUAL_MAIN(Wmu, Wstd)
  float4 bb1 = ((const float4*)bmu)[tx];
  float4 bb2 = ((const float4*)bstd)[tx];
  const float EPS = 1e-9f;
  float klsum = 0.f;
  #pragma unroll
  for (int r = 0; r < 4; ++r){
    int row = row0 + ty*4 + r;
    if (row < n){
      float4 pmv = *(const float4*)(pm + (size_t)row*D + tx*4);
      float4 psv = *(const float4*)(ps + (size_t)row*D + tx*4);
      float em[4], es[4], pmf[4] = {pmv.x,pmv.y,pmv.z,pmv.w}, psf[4] = {psv.x,psv.y,psv.z,psv.w};
      float bmu4[4] = {bb1.x,bb1.y,bb1.z,bb1.w}, bsd4[4] = {bb2.x,bb2.y,bb2.z,bb2.w};
      #pragma unroll
      for (int c = 0; c < 4; ++c){
        em[c] = acc1[r][c] + bmu4[c];
        es[c] = sigmoidf_(acc2[r][c] + bsd4[c]);
        u32 m = (u32)row*128u + (u32)(tx*4 + c);
        float eps = jax_normal_part_xor(m);
        conf[m] = fmaf(eps, es[c], em[c]);
        float es_e = es[c] + EPS, ps_e = psf[c] + EPS;
        float diff = em[c] - pmf[c];
        klsum += 2.0f*__logf(ps_e/es_e)
               + (es_e*es_e + diff*diff) / (ps_e*ps_e) - 1.0f;
      }
    }
  }
  // wave shfl reduce -> LDS -> one write per block
  #pragma unroll
  for (int off = 32; off > 0; off >>= 1) klsum += __shfl_down(klsum, off);
  __shared__ float wsum[4];
  if ((tid & 63) == 0) wsum[tid >> 6] = klsum;
  __syncthreads();
  if (tid == 0) pblk[blockIdx.x] = wsum[0] + wsum[1] + wsum[2] + wsum[3];
}

__global__ __launch_bounds__(256) void k_finish(const float* __restrict__ pblk, int nb,
                                                float* __restrict__ out0, int n){
  __shared__ double sh[256];
  double s = 0.0;
  for (int i = threadIdx.x; i < nb; i += 256) s += (double)pblk[i];
  sh[threadIdx.x] = s; __syncthreads();
  for (int off = 128; off > 0; off >>= 1){
    if (threadIdx.x < off) sh[threadIdx.x] += sh[threadIdx.x + off];
    __syncthreads();
  }
  if (threadIdx.x == 0) out0[0] = (float)(0.5 * sh[0] / (double)n);
}

// ---------------------------------------------------------------------------
extern "C" void kernel_launch(void* const* d_in, const int* in_sizes, int n_in,
                              void* d_out, int out_size, void* d_ws, size_t ws_size,
                              hipStream_t stream){
  const void*  eidx   = d_in[0];
  const float* x      = (const float*)d_in[1];
  const int*   t_ptr  = (const int*)d_in[2];
  const float* escore = (const float*)d_in[3];
  const float* W_enc = (const float*)d_in[6];  const float* b_enc = (const float*)d_in[7];
  const float* W_mu  = (const float*)d_in[8];  const float* b_mu  = (const float*)d_in[9];
  const float* W_std = (const float*)d_in[10]; const float* b_std = (const float*)d_in[11];
  const float* W_pr  = (const float*)d_in[12]; const float* b_pr  = (const float*)d_in[13];
  const float* W_pm  = (const float*)d_in[14]; const float* b_pm  = (const float*)d_in[15];
  const float* W_ps  = (const float*)d_in[16]; const float* b_ps  = (const float*)d_in[17];
  const float* temb  = (const float*)d_in[18];

  const int N = in_sizes[1] / D;
  const int E = in_sizes[3];

  char* w = (char*)d_ws;
  auto alloc = [&](size_t bytes) -> char* {
    char* p = w; w += (bytes + 255) & ~(size_t)255; return p;
  };
  int*    flag   = (int*)   alloc(256);
  int*    src_w  = (int*)   alloc((size_t)E*4);
  int*    dst_w  = (int*)   alloc((size_t)E*4);
  int*    cnt    = (int*)   alloc((size_t)N*4);
  int*    rp     = (int*)   alloc((size_t)(N+1)*4);
  int*    cur    = (int*)   alloc((size_t)N*4);
  float*  dinv_s = (float*) alloc((size_t)N*4);
  float*  dinv_o = (float*) alloc((size_t)N*4);
  int*    bsum   = (int*)   alloc(1024*4);
  int*    col    = (int*)   alloc((size_t)E*4);
  float*  wsrt   = (float*) alloc((size_t)E*4);
  float*  B1     = (float*) alloc((size_t)N*D*4);  // agg_score_x
  float*  B2     = (float*) alloc((size_t)N*D*4);  // agg_ones_x -> agg_ones_enc
  float*  B3     = (float*) alloc((size_t)N*D*4);  // enc_t -> prior_mean
  float*  B4     = (float*) alloc((size_t)N*D*4);  // prior_std
  float*  B5     = (float*) alloc((size_t)N*D*4);  // prior
  const int gG   = (N + 31) / 32;                  // GEMM row tiles (32 rows)
  float*  pblk   = (float*) alloc((size_t)gG*4);   // per-block kl partials
  (void)ws_size; (void)n_in; (void)out_size;

  float* conf = ((float*)d_out) + 1;

  const int gE  = (E + 255) / 256;
  const int gN  = (N + 255) / 256;      // also #scan blocks (196 <= 1024)
  const int gW  = (N * 64 + 255) / 256; // one wave per node

  k_detect <<<1, 256, 0, stream>>>((const u32*)eidx, flag);
  k_norm   <<<gE, 256, 0, stream>>>(eidx, flag, src_w, dst_w, E);
  k_init   <<<gN, 256, 0, stream>>>(cnt, N);
  k_hist   <<<gE, 256, 0, stream>>>(dst_w, cnt, E);
  k_scan1  <<<gN, 256, 0, stream>>>(cnt, rp, bsum, N);
  k_scan2  <<<1, 1024, 0, stream>>>(bsum, gN);
  k_scan3  <<<gN, 256, 0, stream>>>(rp, cur, bsum, cnt, dinv_o, N, E);
  k_scatter<<<gE, 256, 0, stream>>>(src_w, dst_w, escore, cur, col, wsrt, E);
  k_deg    <<<gN, 256, 0, stream>>>(rp, wsrt, dinv_s, N);

  // agg_sx = A_score x -> B1 ; agg_ox = A_ones x -> B2
  k_agg_dual<<<gW, 256, 0, stream>>>(x, rp, col, wsrt, dinv_s, dinv_o, B1, B2, N);
  // y=0: enc_t = relu(B1@W_enc+b_enc) -> B3 ; y=1: prior = relu(B2@W_pr+b_pr)+temb -> B5
  k_gemm_act2<<<dim3(gG,2), 256, 0, stream>>>(B1, W_enc, b_enc, B2, W_pr, b_pr,
                                              temb, t_ptr, B3, B5, N);
  // agg_oe = A_ones enc_t -> B2
  k_agg_one<<<gW, 256, 0, stream>>>(B3, rp, col, dinv_o, B2, N);
  // pm = B5@W_pm + b_pm -> B3 ; ps = sigmoid(B5@W_ps + b_ps) -> B4
  k_gemm_dual<<<gG, 256, 0, stream>>>(B5, W_pm, b_pm, W_ps, b_ps, B3, B4, N);
  // em/es + conf_z + kl partials
  k_gemm_final<<<gG, 256, 0, stream>>>(B2, W_mu, b_mu, W_std, b_std, B3, B4, conf, pblk, N);
  k_finish<<<1, 256, 0, stream>>>(pblk, gG, (float*)d_out, N);
}

// Round 8
// 426.608 us; speedup vs baseline: 1.4135x; 1.4135x over previous
//
#include <hip/hip_runtime.h>
#include <math.h>

#define D 128

typedef unsigned int u32;
typedef unsigned short u16;
typedef __attribute__((ext_vector_type(8))) short bf16x8;   // 8 bf16 (4 VGPRs)
typedef __attribute__((ext_vector_type(4))) float f32x4;    // MFMA C/D
typedef __attribute__((ext_vector_type(4))) u32 u32x4;

__device__ __forceinline__ u32 rotl32(u32 x, int r){ return (x<<r) | (x>>(32-r)); }

__device__ __forceinline__ u16 f2bf(float x){                // round-to-nearest-even
  u32 u = __float_as_uint(x);
  return (u16)((u + 0x7fffu + ((u >> 16) & 1u)) >> 16);
}
__device__ __forceinline__ float bf2f(u16 h){ return __uint_as_float(((u32)h) << 16); }

// eps = jax.random.normal(jax.random.key(42), ...), element m (row-major flat).
// Threefry PARTITIONABLE: counter (0,m), key (0,42); bits = x0^x1.  [verified R3]
__device__ __forceinline__ float jax_normal_part_xor(u32 m){
  const u32 ks0 = 0u, ks1 = 42u, ks2 = 0x1BD11BF0u;
  u32 x0 = 0u + ks0;
  u32 x1 = m  + ks1;
  #define TF_R4(a,b,c,d) \
    x0 += x1; x1 = rotl32(x1,(a)); x1 ^= x0; \
    x0 += x1; x1 = rotl32(x1,(b)); x1 ^= x0; \
    x0 += x1; x1 = rotl32(x1,(c)); x1 ^= x0; \
    x0 += x1; x1 = rotl32(x1,(d)); x1 ^= x0;
  TF_R4(13,15,26,6)   x0 += ks1; x1 += ks2 + 1u;
  TF_R4(17,29,16,24)  x0 += ks2; x1 += ks0 + 2u;
  TF_R4(13,15,26,6)   x0 += ks0; x1 += ks1 + 3u;
  TF_R4(17,29,16,24)  x0 += ks1; x1 += ks2 + 4u;
  TF_R4(13,15,26,6)   x0 += ks2; x1 += ks0 + 5u;
  #undef TF_R4
  u32 bits = x0 ^ x1;
  float f = __uint_as_float((bits >> 9) | 0x3F800000u) - 1.0f;
  const float LO = -0.99999994f;
  float u = fmaxf(LO, f * 2.0f + LO);
  float w = -log1pf(-u*u);
  float p;
  if (w < 5.0f){
    w -= 2.5f;
    p =  2.81022636e-08f;
    p = fmaf(p, w,  3.43273939e-07f);
    p = fmaf(p, w, -3.5233877e-06f);
    p = fmaf(p, w, -4.39150654e-06f);
    p = fmaf(p, w,  0.00021858087f);
    p = fmaf(p, w, -0.00125372503f);
    p = fmaf(p, w, -0.00417768164f);
    p = fmaf(p, w,  0.246640727f);
    p = fmaf(p, w,  1.50140941f);
  } else {
    w = sqrtf(w) - 3.0f;
    p = -0.000200214257f;
    p = fmaf(p, w,  0.000100950558f);
    p = fmaf(p, w,  0.00134934322f);
    p = fmaf(p, w, -0.00367342844f);
    p = fmaf(p, w,  0.00573950773f);
    p = fmaf(p, w, -0.0076224613f);
    p = fmaf(p, w,  0.00943887047f);
    p = fmaf(p, w,  1.00167406f);
    p = fmaf(p, w,  2.83297682f);
  }
  return 1.41421354f * (p * u);
}

__device__ __forceinline__ float sigmoidf_(float z){ return 1.0f / (1.0f + __expf(-z)); }

// ---------------- index normalization ----------------
__global__ void k_detect(const u32* __restrict__ e_u32, int* __restrict__ flag){
  __shared__ int s_nz;
  if (threadIdx.x == 0) s_nz = 0;
  __syncthreads();
  if (e_u32[2*threadIdx.x + 1] != 0u) atomicAdd(&s_nz, 1);
  __syncthreads();
  if (threadIdx.x == 0) *flag = (s_nz == 0) ? 1 : 0;
}

__global__ void k_norm(const void* __restrict__ eidx, const int* __restrict__ flag,
                       int* __restrict__ src_w, int* __restrict__ dst_w, int e){
  int i = blockIdx.x*256 + threadIdx.x;
  if (i >= e) return;
  if (*flag){
    const u32* u = (const u32*)eidx;
    src_w[i] = (int)u[2*(size_t)i];
    dst_w[i] = (int)u[2*((size_t)e + i)];
  } else {
    const int* p = (const int*)eidx;
    src_w[i] = p[i];
    dst_w[i] = p[e + i];
  }
}

// ---------------- CSR build (int atomics only) ----------------
__global__ void k_init(int* __restrict__ cnt, int n){
  int i = blockIdx.x*256 + threadIdx.x;
  if (i < n) cnt[i] = 0;
}

__global__ void k_hist(const int* __restrict__ dst, int* __restrict__ cnt, int e){
  int i = blockIdx.x*256 + threadIdx.x;
  if (i >= e) return;
  atomicAdd(&cnt[dst[i]], 1);
}

__global__ __launch_bounds__(256) void k_scan1(const int* __restrict__ cnt,
                                               int* __restrict__ rp,
                                               int* __restrict__ bsum, int n){
  __shared__ int sh[256];
  int tid = threadIdx.x, idx = blockIdx.x*256 + tid;
  int v = (idx < n) ? cnt[idx] : 0;
  sh[tid] = v; __syncthreads();
  for (int off = 1; off < 256; off <<= 1){
    int t = (tid >= off) ? sh[tid-off] : 0;
    __syncthreads(); sh[tid] += t; __syncthreads();
  }
  if (idx < n) rp[idx] = sh[tid] - v;
  if (tid == 255) bsum[blockIdx.x] = sh[255];
}

__global__ __launch_bounds__(1024) void k_scan2(int* __restrict__ bsum, int nb){
  __shared__ int sh[1024];
  int tid = threadIdx.x;
  int v = (tid < nb) ? bsum[tid] : 0;
  sh[tid] = v; __syncthreads();
  for (int off = 1; off < 1024; off <<= 1){
    int t = (tid >= off) ? sh[tid-off] : 0;
    __syncthreads(); sh[tid] += t; __syncthreads();
  }
  if (tid < nb) bsum[tid] = sh[tid] - v;
}

__global__ void k_scan3(int* __restrict__ rp, int* __restrict__ cur,
                        const int* __restrict__ bsum, const int* __restrict__ cnt,
                        float* __restrict__ dinv_o, int n, int e){
  int idx = blockIdx.x*256 + threadIdx.x;
  if (idx < n){
    int r = rp[idx] + bsum[blockIdx.x];
    rp[idx] = r; cur[idx] = r;
    dinv_o[idx] = rsqrtf((float)(cnt[idx] + 1));
  }
  if (idx == 0) rp[n] = e;
}

__global__ void k_scatter(const int* __restrict__ src, const int* __restrict__ dst,
                          const float* __restrict__ sc, int* __restrict__ cur,
                          int* __restrict__ col, float* __restrict__ wsrt, int e){
  int i = blockIdx.x*256 + threadIdx.x;
  if (i >= e) return;
  int d = dst[i];
  int p = atomicAdd(&cur[d], 1);
  col[p] = src[i];
  wsrt[p] = sc[i];
}

__global__ void k_deg(const int* __restrict__ rp, const float* __restrict__ wsrt,
                      float* __restrict__ dinv_s, int n){
  int i = blockIdx.x*256 + threadIdx.x;
  if (i >= n) return;
  float s = 1.0f;
  int e0 = rp[i], e1 = rp[i+1];
  for (int j = e0; j < e1; ++j) s += wsrt[j];
  dinv_s[i] = rsqrtf(s);
}

// ---------------- weight convert: fp32 W[k][col] -> bf16 Wt[col][k], 6 mats ----
__global__ void k_wconv(const float* __restrict__ W0, const float* __restrict__ W1,
                        const float* __restrict__ W2, const float* __restrict__ W3,
                        const float* __restrict__ W4, const float* __restrict__ W5,
                        u16* __restrict__ wt){
  const float* Ws[6] = {W0,W1,W2,W3,W4,W5};
  const float* W = Ws[blockIdx.y];
  u16* Wt = wt + (size_t)blockIdx.y*16384;
  int idx = blockIdx.x*256 + threadIdx.x;          // = k*128 + col
  int k = idx >> 7, col = idx & 127;
  Wt[col*128 + k] = f2bf(W[idx]);
}

// ---------------- aggregations: one wave per node ----------------
__global__ __launch_bounds__(256) void k_agg_dual(
    const float* __restrict__ x, const int* __restrict__ rp,
    const int* __restrict__ col, const float* __restrict__ wsrt,
    const float* __restrict__ dinv_s, const float* __restrict__ dinv_o,
    u16* __restrict__ out_s, u16* __restrict__ out_o, int n){
  int wid = (blockIdx.x * 256 + threadIdx.x) >> 6;
  int lane = threadIdx.x & 63;
  if (wid >= n) return;
  const float2* x2 = (const float2*)x;
  float dsv = dinv_s[wid], dov = dinv_o[wid];
  float2 xv = x2[(size_t)wid*64 + lane];
  float ss = dsv*dsv, oo = dov*dov;
  float2 as = { xv.x*ss, xv.y*ss };
  float2 ao = { xv.x*oo, xv.y*oo };
  int e0 = rp[wid], e1 = rp[wid+1];
  for (int base = e0; base < e1; base += 64){
    int cnt = e1 - base; if (cnt > 64) cnt = 64;
    int idx = base + (lane < cnt ? lane : cnt - 1);
    int   sl = col[idx];
    float wl = wsrt[idx];
    float nsl = dinv_s[sl] * wl * dsv;
    float nol = dinv_o[sl] * dov;
    int j = 0;
    for (; j + 4 <= cnt; j += 4){
      int   s0=__shfl(sl,j),   s1=__shfl(sl,j+1),   s2=__shfl(sl,j+2),   s3=__shfl(sl,j+3);
      float a0=__shfl(nsl,j),  a1=__shfl(nsl,j+1),  a2=__shfl(nsl,j+2),  a3=__shfl(nsl,j+3);
      float b0=__shfl(nol,j),  b1=__shfl(nol,j+1),  b2=__shfl(nol,j+2),  b3=__shfl(nol,j+3);
      float2 r0 = x2[(size_t)s0*64 + lane];
      float2 r1 = x2[(size_t)s1*64 + lane];
      float2 r2 = x2[(size_t)s2*64 + lane];
      float2 r3 = x2[(size_t)s3*64 + lane];
      as.x = fmaf(a0,r0.x,as.x); as.y = fmaf(a0,r0.y,as.y);
      ao.x = fmaf(b0,r0.x,ao.x); ao.y = fmaf(b0,r0.y,ao.y);
      as.x = fmaf(a1,r1.x,as.x); as.y = fmaf(a1,r1.y,as.y);
      ao.x = fmaf(b1,r1.x,ao.x); ao.y = fmaf(b1,r1.y,ao.y);
      as.x = fmaf(a2,r2.x,as.x); as.y = fmaf(a2,r2.y,as.y);
      ao.x = fmaf(b2,r2.x,ao.x); ao.y = fmaf(b2,r2.y,ao.y);
      as.x = fmaf(a3,r3.x,as.x); as.y = fmaf(a3,r3.y,as.y);
      ao.x = fmaf(b3,r3.x,ao.x); ao.y = fmaf(b3,r3.y,ao.y);
    }
    for (; j < cnt; ++j){
      int   s0=__shfl(sl,j);
      float a0=__shfl(nsl,j), b0=__shfl(nol,j);
      float2 r0 = x2[(size_t)s0*64 + lane];
      as.x = fmaf(a0,r0.x,as.x); as.y = fmaf(a0,r0.y,as.y);
      ao.x = fmaf(b0,r0.x,ao.x); ao.y = fmaf(b0,r0.y,ao.y);
    }
  }
  ((u32*)out_s)[(size_t)wid*64 + lane] = (u32)f2bf(as.x) | ((u32)f2bf(as.y) << 16);
  ((u32*)out_o)[(size_t)wid*64 + lane] = (u32)f2bf(ao.x) | ((u32)f2bf(ao.y) << 16);
}

// bf16 gather input (enc_t), bf16 output
__global__ __launch_bounds__(256) void k_agg_one(
    const u16* __restrict__ h, const int* __restrict__ rp,
    const int* __restrict__ col, const float* __restrict__ dinv_o,
    u16* __restrict__ out, int n){
  int wid = (blockIdx.x * 256 + threadIdx.x) >> 6;
  int lane = threadIdx.x & 63;
  if (wid >= n) return;
  const u32* h2 = (const u32*)h;
  float dov = dinv_o[wid];
  u32 hv = h2[(size_t)wid*64 + lane];
  float oo = dov*dov;
  float2 ao = { bf2f((u16)(hv & 0xffff))*oo, bf2f((u16)(hv >> 16))*oo };
  int e0 = rp[wid], e1 = rp[wid+1];
  for (int base = e0; base < e1; base += 64){
    int cnt = e1 - base; if (cnt > 64) cnt = 64;
    int idx = base + (lane < cnt ? lane : cnt - 1);
    int   sl = col[idx];
    float nol = dinv_o[sl] * dov;
    int j = 0;
    for (; j + 4 <= cnt; j += 4){
      int   s0=__shfl(sl,j),  s1=__shfl(sl,j+1),  s2=__shfl(sl,j+2),  s3=__shfl(sl,j+3);
      float b0=__shfl(nol,j), b1=__shfl(nol,j+1), b2=__shfl(nol,j+2), b3=__shfl(nol,j+3);
      u32 r0 = h2[(size_t)s0*64 + lane];
      u32 r1 = h2[(size_t)s1*64 + lane];
      u32 r2 = h2[(size_t)s2*64 + lane];
      u32 r3 = h2[(size_t)s3*64 + lane];
      ao.x = fmaf(b0, bf2f((u16)(r0&0xffff)), ao.x); ao.y = fmaf(b0, bf2f((u16)(r0>>16)), ao.y);
      ao.x = fmaf(b1, bf2f((u16)(r1&0xffff)), ao.x); ao.y = fmaf(b1, bf2f((u16)(r1>>16)), ao.y);
      ao.x = fmaf(b2, bf2f((u16)(r2&0xffff)), ao.x); ao.y = fmaf(b2, bf2f((u16)(r2>>16)), ao.y);
      ao.x = fmaf(b3, bf2f((u16)(r3&0xffff)), ao.x); ao.y = fmaf(b3, bf2f((u16)(r3>>16)), ao.y);
    }
    for (; j < cnt; ++j){
      int   s0=__shfl(sl,j);
      float b0=__shfl(nol,j);
      u32 r0 = h2[(size_t)s0*64 + lane];
      ao.x = fmaf(b0, bf2f((u16)(r0&0xffff)), ao.x); ao.y = fmaf(b0, bf2f((u16)(r0>>16)), ao.y);
    }
  }
  ((u32*)out)[(size_t)wid*64 + lane] = (u32)f2bf(ao.x) | ((u32)f2bf(ao.y) << 16);
}

// ---------------- MFMA GEMMs: 64-row tile, 4 waves, bf16 16x16x32 -------------
// A_lds [64 rows][128 k] bf16 (256B/row), W_lds [128 cols][64 k] bf16 (128B/row),
// both XOR-swizzled: byte_in_row ^= (row&7)<<4 (write & read use same involution).
// Frags: A row=lane&15, k=(lane>>4)*8+j ; B col=lane&15 (Wt transposed);
// C/D col=lane&15, row=(lane>>4)*4+reg [m89].

#define STAGE_A_BF(Abf)                                                        \
  for (int c = tid; c < 1024; c += 256){                                       \
    int row = c >> 4, kb = (c & 15) << 4;                                      \
    u32x4 v = {0,0,0,0};                                                       \
    int g = row0 + row;                                                        \
    if (g < n) v = *(const u32x4*)((const char*)(Abf) + (size_t)g*256 + kb);   \
    *(u32x4*)((char*)A_lds + row*256 + (kb ^ ((row & 7) << 4))) = v;           \
  }

// stage half h (k in [h*64,(h+1)*64)) of one transposed weight: 128 cols x 128 B
#define STAGE_W_HALF(Wt_, Wl_)                                                 \
  for (int c = tid; c < 1024; c += 256){                                       \
    int colw = c >> 3, kb = (c & 7) << 4;                                      \
    u32x4 v = *(const u32x4*)((const char*)(Wt_) + (size_t)colw*256 + h*128 + kb); \
    *(u32x4*)((char*)(Wl_) + colw*128 + (kb ^ ((colw & 7) << 4))) = v;         \
  }

__global__ __launch_bounds__(256) void k_mfma_act2(
    const u16* __restrict__ A0, const u16* __restrict__ Wt0, const float* __restrict__ b0,
    const u16* __restrict__ A1, const u16* __restrict__ Wt1, const float* __restrict__ b1,
    const float* __restrict__ temb, const int* __restrict__ t_ptr,
    u16* __restrict__ out0, u16* __restrict__ out1, int n){
  __shared__ u32 A_lds[4096];    // 16 KB
  __shared__ u32 W_lds[4096];    // 16 KB: 128 cols x 128 B (one k-half)
  const int sl = blockIdx.y;
  const u16* A  = sl ? A1 : A0;
  const u16* Wt = sl ? Wt1 : Wt0;
  const float* b = sl ? b1 : b0;
  u16* out = sl ? out1 : out0;
  const int tid = threadIdx.x;
  const int row0 = blockIdx.x * 64;
  STAGE_A_BF(A)
  const int lane = tid & 63, wave = tid >> 6;
  const int lr = lane & 15, lg = lane >> 4;
  f32x4 z = {0.f,0.f,0.f,0.f};
  f32x4 acc[8];
  #pragma unroll
  for (int i = 0; i < 8; ++i) acc[i] = z;
  for (int h = 0; h < 2; ++h){
    __syncthreads();
    STAGE_W_HALF(Wt, W_lds)
    __syncthreads();
    #pragma unroll
    for (int ksl = 0; ksl < 2; ++ksl){
      int arow = wave*16 + lr;
      bf16x8 a = *(bf16x8*)((char*)A_lds + arow*256
                   + ((((h*2+ksl)*64) + lg*16) ^ ((arow & 7) << 4)));
      #pragma unroll
      for (int cf = 0; cf < 8; ++cf){
        int colw = cf*16 + lr;
        int wb = colw*128 + (((ksl*64) + lg*16) ^ ((colw & 7) << 4));
        bf16x8 bb = *(bf16x8*)((char*)W_lds + wb);
        acc[cf] = __builtin_amdgcn_mfma_f32_16x16x32_bf16(a, bb, acc[cf], 0, 0, 0);
      }
    }
  }
  int t = sl ? *t_ptr : 0;
  int rbase = row0 + wave*16 + (lg << 2);
  #pragma unroll
  for (int cf = 0; cf < 8; ++cf){
    int colw = cf*16 + lr;
    float bb = b[colw];
    float tt = sl ? temb[t*128 + colw] : 0.f;
    #pragma unroll
    for (int r = 0; r < 4; ++r){
      int row = rbase + r;
      if (row < n)
        out[(size_t)row*128 + colw] = f2bf(fmaxf(acc[cf][r] + bb, 0.f) + tt);
    }
  }
}

// dual: out1 = A@W1+b1 (linear), out2 = sigmoid(A@W2+b2); all bf16 I/O
__global__ __launch_bounds__(256) void k_mfma_dual(
    const u16* __restrict__ A, const u16* __restrict__ Wt1, const float* __restrict__ b1,
    const u16* __restrict__ Wt2, const float* __restrict__ b2,
    u16* __restrict__ out1, u16* __restrict__ out2, int n){
  __shared__ u32 A_lds[4096];
  __shared__ u32 W1_lds[4096];
  __shared__ u32 W2_lds[4096];
  const int tid = threadIdx.x;
  const int row0 = blockIdx.x * 64;
  STAGE_A_BF(A)
  const int lane = tid & 63, wave = tid >> 6;
  const int lr = lane & 15, lg = lane >> 4;
  f32x4 z = {0.f,0.f,0.f,0.f};
  f32x4 acc1[8], acc2[8];
  #pragma unroll
  for (int i = 0; i < 8; ++i){ acc1[i] = z; acc2[i] = z; }
  for (int h = 0; h < 2; ++h){
    __syncthreads();
    STAGE_W_HALF(Wt1, W1_lds)
    STAGE_W_HALF(Wt2, W2_lds)
    __syncthreads();
    #pragma unroll
    for (int ksl = 0; ksl < 2; ++ksl){
      int arow = wave*16 + lr;
      bf16x8 a = *(bf16x8*)((char*)A_lds + arow*256
                   + ((((h*2+ksl)*64) + lg*16) ^ ((arow & 7) << 4)));
      #pragma unroll
      for (int cf = 0; cf < 8; ++cf){
        int colw = cf*16 + lr;
        int wb = colw*128 + (((ksl*64) + lg*16) ^ ((colw & 7) << 4));
        bf16x8 bb1 = *(bf16x8*)((char*)W1_lds + wb);
        acc1[cf] = __builtin_amdgcn_mfma_f32_16x16x32_bf16(a, bb1, acc1[cf], 0, 0, 0);
        bf16x8 bb2 = *(bf16x8*)((char*)W2_lds + wb);
        acc2[cf] = __builtin_amdgcn_mfma_f32_16x16x32_bf16(a, bb2, acc2[cf], 0, 0, 0);
      }
    }
  }
  int rbase = row0 + wave*16 + (lg << 2);
  #pragma unroll
  for (int cf = 0; cf < 8; ++cf){
    int colw = cf*16 + lr;
    float bb1 = b1[colw], bb2 = b2[colw];
    #pragma unroll
    for (int r = 0; r < 4; ++r){
      int row = rbase + r;
      if (row < n){
        out1[(size_t)row*128 + colw] = f2bf(acc1[cf][r] + bb1);
        out2[(size_t)row*128 + colw] = f2bf(sigmoidf_(acc2[cf][r] + bb2));
      }
    }
  }
}

// final: em = A@Wmu+bmu, es = sigmoid(A@Wstd+bstd); conf = eps*es+em (fp32 out);
// kl partials -> pblk
__global__ __launch_bounds__(256) void k_mfma_final(
    const u16* __restrict__ A, const u16* __restrict__ Wtmu, const float* __restrict__ bmu,
    const u16* __restrict__ Wtstd, const float* __restrict__ bstd,
    const u16* __restrict__ pm, const u16* __restrict__ ps,
    float* __restrict__ conf, float* __restrict__ pblk, int n){
  __shared__ u32 A_lds[4096];
  __shared__ u32 W1_lds[4096];
  __shared__ u32 W2_lds[4096];
  const int tid = threadIdx.x;
  const int row0 = blockIdx.x * 64;
  STAGE_A_BF(A)
  const int lane = tid & 63, wave = tid >> 6;
  const int lr = lane & 15, lg = lane >> 4;
  f32x4 z = {0.f,0.f,0.f,0.f};
  f32x4 acc1[8], acc2[8];
  #pragma unroll
  for (int i = 0; i < 8; ++i){ acc1[i] = z; acc2[i] = z; }
  for (int h = 0; h < 2; ++h){
    __syncthreads();
    STAGE_W_HALF(Wtmu, W1_lds)
    STAGE_W_HALF(Wtstd, W2_lds)
    __syncthreads();
    #pragma unroll
    for (int ksl = 0; ksl < 2; ++ksl){
      int arow = wave*16 + lr;
      bf16x8 a = *(bf16x8*)((char*)A_lds + arow*256
                   + ((((h*2+ksl)*64) + lg*16) ^ ((arow & 7) << 4)));
      #pragma unroll
      for (int cf = 0; cf < 8; ++cf){
        int colw = cf*16 + lr;
        int wb = colw*128 + (((ksl*64) + lg*16) ^ ((colw & 7) << 4));
        bf16x8 bb1 = *(bf16x8*)((char*)W1_lds + wb);
        acc1[cf] = __builtin_amdgcn_mfma_f32_16x16x32_bf16(a, bb1, acc1[cf], 0, 0, 0);
        bf16x8 bb2 = *(bf16x8*)((char*)W2_lds + wb);
        acc2[cf] = __builtin_amdgcn_mfma_f32_16x16x32_bf16(a, bb2, acc2[cf], 0, 0, 0);
      }
    }
  }
  const float EPS = 1e-9f;
  int rbase = row0 + wave*16 + (lg << 2);
  float klsum = 0.f;
  #pragma unroll
  for (int cf = 0; cf < 8; ++cf){
    int colw = cf*16 + lr;
    float bb1 = bmu[colw], bb2 = bstd[colw];
    #pragma unroll
    for (int r = 0; r < 4; ++r){
      int row = rbase + r;
      if (row < n){
        size_t m = (size_t)row*128 + colw;
        float em = acc1[cf][r] + bb1;
        float es = sigmoidf_(acc2[cf][r] + bb2);
        float eps = jax_normal_part_xor((u32)m);
        conf[m] = fmaf(eps, es, em);
        float pmv = bf2f(pm[m]), psv = bf2f(ps[m]);
        float es_e = es + EPS, ps_e = psv + EPS;
        float diff = em - pmv;
        klsum += 2.0f*__logf(ps_e/es_e)
               + (es_e*es_e + diff*diff) / (ps_e*ps_e) - 1.0f;
      }
    }
  }
  #pragma unroll
  for (int off = 32; off > 0; off >>= 1) klsum += __shfl_down(klsum, off);
  __shared__ float wsum[4];
  if ((tid & 63) == 0) wsum[tid >> 6] = klsum;
  __syncthreads();
  if (tid == 0) pblk[blockIdx.x] = wsum[0] + wsum[1] + wsum[2] + wsum[3];
}

__global__ __launch_bounds__(256) void k_finish(const float* __restrict__ pblk, int nb,
                                                float* __restrict__ out0, int n){
  __shared__ double sh[256];
  double s = 0.0;
  for (int i = threadIdx.x; i < nb; i += 256) s += (double)pblk[i];
  sh[threadIdx.x] = s; __syncthreads();
  for (int off = 128; off > 0; off >>= 1){
    if (threadIdx.x < off) sh[threadIdx.x] += sh[threadIdx.x + off];
    __syncthreads();
  }
  if (threadIdx.x == 0) out0[0] = (float)(0.5 * sh[0] / (double)n);
}

// ---------------------------------------------------------------------------
extern "C" void kernel_launch(void* const* d_in, const int* in_sizes, int n_in,
                              void* d_out, int out_size, void* d_ws, size_t ws_size,
                              hipStream_t stream){
  const void*  eidx   = d_in[0];
  const float* x      = (const float*)d_in[1];
  const int*   t_ptr  = (const int*)d_in[2];
  const float* escore = (const float*)d_in[3];
  const float* W_enc = (const float*)d_in[6];  const float* b_enc = (const float*)d_in[7];
  const float* W_mu  = (const float*)d_in[8];  const float* b_mu  = (const float*)d_in[9];
  const float* W_std = (const float*)d_in[10]; const float* b_std = (const float*)d_in[11];
  const float* W_pr  = (const float*)d_in[12]; const float* b_pr  = (const float*)d_in[13];
  const float* W_pm  = (const float*)d_in[14]; const float* b_pm  = (const float*)d_in[15];
  const float* W_ps  = (const float*)d_in[16]; const float* b_ps  = (const float*)d_in[17];
  const float* temb  = (const float*)d_in[18];

  const int N = in_sizes[1] / D;
  const int E = in_sizes[3];

  char* w = (char*)d_ws;
  auto alloc = [&](size_t bytes) -> char* {
    char* p = w; w += (bytes + 255) & ~(size_t)255; return p;
  };
  int*    flag   = (int*)   alloc(256);
  int*    src_w  = (int*)   alloc((size_t)E*4);
  int*    dst_w  = (int*)   alloc((size_t)E*4);
  int*    cnt    = (int*)   alloc((size_t)N*4);
  int*    rp     = (int*)   alloc((size_t)(N+1)*4);
  int*    cur    = (int*)   alloc((size_t)N*4);
  float*  dinv_s = (float*) alloc((size_t)N*4);
  float*  dinv_o = (float*) alloc((size_t)N*4);
  int*    bsum   = (int*)   alloc(1024*4);
  int*    col    = (int*)   alloc((size_t)E*4);
  float*  wsrt   = (float*) alloc((size_t)E*4);
  u16*    wt     = (u16*)   alloc((size_t)6*16384*2);  // 6 transposed bf16 weights
  u16*    B1     = (u16*)   alloc((size_t)N*D*2);  // agg_score_x (bf16)
  u16*    B2     = (u16*)   alloc((size_t)N*D*2);  // agg_ones_x -> agg_ones_enc
  u16*    B3     = (u16*)   alloc((size_t)N*D*2);  // enc_t -> pm
  u16*    B4     = (u16*)   alloc((size_t)N*D*2);  // ps
  u16*    B5     = (u16*)   alloc((size_t)N*D*2);  // prior
  const int gG64 = (N + 63) / 64;                  // MFMA tiles (64 rows)
  float*  pblk   = (float*) alloc((size_t)gG64*4);
  (void)ws_size; (void)n_in; (void)out_size;

  float* conf = ((float*)d_out) + 1;

  u16* Wt_enc = wt + 0*16384;
  u16* Wt_pr  = wt + 1*16384;
  u16* Wt_pm  = wt + 2*16384;
  u16* Wt_ps  = wt + 3*16384;
  u16* Wt_mu  = wt + 4*16384;
  u16* Wt_std = wt + 5*16384;

  const int gE  = (E + 255) / 256;
  const int gN  = (N + 255) / 256;
  const int gW  = (N * 64 + 255) / 256;

  k_wconv <<<dim3(64,6), 256, 0, stream>>>(W_enc, W_pr, W_pm, W_ps, W_mu, W_std, wt);
  k_detect <<<1, 256, 0, stream>>>((const u32*)eidx, flag);
  k_norm   <<<gE, 256, 0, stream>>>(eidx, flag, src_w, dst_w, E);
  k_init   <<<gN, 256, 0, stream>>>(cnt, N);
  k_hist   <<<gE, 256, 0, stream>>>(dst_w, cnt, E);
  k_scan1  <<<gN, 256, 0, stream>>>(cnt, rp, bsum, N);
  k_scan2  <<<1, 1024, 0, stream>>>(bsum, gN);
  k_scan3  <<<gN, 256, 0, stream>>>(rp, cur, bsum, cnt, dinv_o, N, E);
  k_scatter<<<gE, 256, 0, stream>>>(src_w, dst_w, escore, cur, col, wsrt, E);
  k_deg    <<<gN, 256, 0, stream>>>(rp, wsrt, dinv_s, N);

  // agg_sx -> B1 (bf16) ; agg_ox -> B2 (bf16)
  k_agg_dual<<<gW, 256, 0, stream>>>(x, rp, col, wsrt, dinv_s, dinv_o, B1, B2, N);
  // y=0: enc_t = relu(B1@Wenc+b) -> B3 ; y=1: prior = relu(B2@Wpr+b)+temb -> B5
  k_mfma_act2<<<dim3(gG64,2), 256, 0, stream>>>(B1, Wt_enc, b_enc, B2, Wt_pr, b_pr,
                                                temb, t_ptr, B3, B5, N);
  // agg_oe = A_ones enc_t -> B2 (bf16 gather)
  k_agg_one<<<gW, 256, 0, stream>>>(B3, rp, col, dinv_o, B2, N);
  // pm -> B3 ; ps -> B4
  k_mfma_dual<<<gG64, 256, 0, stream>>>(B5, Wt_pm, b_pm, Wt_ps, b_ps, B3, B4, N);
  // em/es + conf + kl partials
  k_mfma_final<<<gG64, 256, 0, stream>>>(B2, Wt_mu, b_mu, Wt_std, b_std, B3, B4,
                                         conf, pblk, N);
  k_finish<<<1, 256, 0, stream>>>(pblk, gG64, (float*)d_out, N);
}

// Round 9
// 384.325 us; speedup vs baseline: 1.5690x; 1.1100x over previous
//
#include <hip/hip_runtime.h>
#include <math.h>

#define D 128

typedef unsigned int u32;
typedef unsigned short u16;
typedef __attribute__((ext_vector_type(8))) short bf16x8;   // 8 bf16 (4 VGPRs)
typedef __attribute__((ext_vector_type(4))) float f32x4;    // MFMA C/D
typedef __attribute__((ext_vector_type(4))) u32 u32x4;

__device__ __forceinline__ u32 rotl32(u32 x, int r){ return (x<<r) | (x>>(32-r)); }

__device__ __forceinline__ u16 f2bf(float x){                // round-to-nearest-even
  u32 u = __float_as_uint(x);
  return (u16)((u + 0x7fffu + ((u >> 16) & 1u)) >> 16);
}
__device__ __forceinline__ float bf2f(u16 h){ return __uint_as_float(((u32)h) << 16); }

// eps = jax.random.normal(jax.random.key(42), ...), element m (row-major flat).
// Threefry PARTITIONABLE: counter (0,m), key (0,42); bits = x0^x1.  [verified R3]
// log1p replaced by fma+v_log (single-rounding 1-u*u is exact enough; err ~1e-5).
__device__ __forceinline__ float jax_normal_part_xor(u32 m){
  const u32 ks0 = 0u, ks1 = 42u, ks2 = 0x1BD11BF0u;
  u32 x0 = 0u + ks0;
  u32 x1 = m  + ks1;
  #define TF_R4(a,b,c,d) \
    x0 += x1; x1 = rotl32(x1,(a)); x1 ^= x0; \
    x0 += x1; x1 = rotl32(x1,(b)); x1 ^= x0; \
    x0 += x1; x1 = rotl32(x1,(c)); x1 ^= x0; \
    x0 += x1; x1 = rotl32(x1,(d)); x1 ^= x0;
  TF_R4(13,15,26,6)   x0 += ks1; x1 += ks2 + 1u;
  TF_R4(17,29,16,24)  x0 += ks2; x1 += ks0 + 2u;
  TF_R4(13,15,26,6)   x0 += ks0; x1 += ks1 + 3u;
  TF_R4(17,29,16,24)  x0 += ks1; x1 += ks2 + 4u;
  TF_R4(13,15,26,6)   x0 += ks2; x1 += ks0 + 5u;
  #undef TF_R4
  u32 bits = x0 ^ x1;
  float f = __uint_as_float((bits >> 9) | 0x3F800000u) - 1.0f;
  const float LO = -0.99999994f;
  float u = fmaxf(LO, f * 2.0f + LO);
  float w = -__logf(fmaf(-u, u, 1.0f));       // = -log(1-u^2)
  float p;
  if (w < 5.0f){
    w -= 2.5f;
    p =  2.81022636e-08f;
    p = fmaf(p, w,  3.43273939e-07f);
    p = fmaf(p, w, -3.5233877e-06f);
    p = fmaf(p, w, -4.39150654e-06f);
    p = fmaf(p, w,  0.00021858087f);
    p = fmaf(p, w, -0.00125372503f);
    p = fmaf(p, w, -0.00417768164f);
    p = fmaf(p, w,  0.246640727f);
    p = fmaf(p, w,  1.50140941f);
  } else {
    w = sqrtf(w) - 3.0f;
    p = -0.000200214257f;
    p = fmaf(p, w,  0.000100950558f);
    p = fmaf(p, w,  0.00134934322f);
    p = fmaf(p, w, -0.00367342844f);
    p = fmaf(p, w,  0.00573950773f);
    p = fmaf(p, w, -0.0076224613f);
    p = fmaf(p, w,  0.00943887047f);
    p = fmaf(p, w,  1.00167406f);
    p = fmaf(p, w,  2.83297682f);
  }
  return 1.41421354f * (p * u);
}

__device__ __forceinline__ float sigmoidf_(float z){ return 1.0f / (1.0f + __expf(-z)); }

// ---------------- index normalization ----------------
__global__ void k_detect(const u32* __restrict__ e_u32, int* __restrict__ flag){
  __shared__ int s_nz;
  if (threadIdx.x == 0) s_nz = 0;
  __syncthreads();
  if (e_u32[2*threadIdx.x + 1] != 0u) atomicAdd(&s_nz, 1);
  __syncthreads();
  if (threadIdx.x == 0) *flag = (s_nz == 0) ? 1 : 0;
}

__global__ void k_norm(const void* __restrict__ eidx, const int* __restrict__ flag,
                       int* __restrict__ src_w, int* __restrict__ dst_w, int e){
  int i = blockIdx.x*256 + threadIdx.x;
  if (i >= e) return;
  if (*flag){
    const u32* u = (const u32*)eidx;
    src_w[i] = (int)u[2*(size_t)i];
    dst_w[i] = (int)u[2*((size_t)e + i)];
  } else {
    const int* p = (const int*)eidx;
    src_w[i] = p[i];
    dst_w[i] = p[e + i];
  }
}

// ---------------- CSR build (int atomics only) ----------------
__global__ void k_init(int* __restrict__ cnt, int n){
  int i = blockIdx.x*256 + threadIdx.x;
  if (i < n) cnt[i] = 0;
}

__global__ void k_hist(const int* __restrict__ dst, int* __restrict__ cnt, int e){
  int i = blockIdx.x*256 + threadIdx.x;
  if (i >= e) return;
  atomicAdd(&cnt[dst[i]], 1);
}

__global__ __launch_bounds__(256) void k_scan1(const int* __restrict__ cnt,
                                               int* __restrict__ rp,
                                               int* __restrict__ bsum, int n){
  __shared__ int sh[256];
  int tid = threadIdx.x, idx = blockIdx.x*256 + tid;
  int v = (idx < n) ? cnt[idx] : 0;
  sh[tid] = v; __syncthreads();
  for (int off = 1; off < 256; off <<= 1){
    int t = (tid >= off) ? sh[tid-off] : 0;
    __syncthreads(); sh[tid] += t; __syncthreads();
  }
  if (idx < n) rp[idx] = sh[tid] - v;
  if (tid == 255) bsum[blockIdx.x] = sh[255];
}

__global__ __launch_bounds__(1024) void k_scan2(int* __restrict__ bsum, int nb){
  __shared__ int sh[1024];
  int tid = threadIdx.x;
  int v = (tid < nb) ? bsum[tid] : 0;
  sh[tid] = v; __syncthreads();
  for (int off = 1; off < 1024; off <<= 1){
    int t = (tid >= off) ? sh[tid-off] : 0;
    __syncthreads(); sh[tid] += t; __syncthreads();
  }
  if (tid < nb) bsum[tid] = sh[tid] - v;
}

__global__ void k_scan3(int* __restrict__ rp, int* __restrict__ cur,
                        const int* __restrict__ bsum, const int* __restrict__ cnt,
                        float* __restrict__ dinv_o, int n, int e){
  int idx = blockIdx.x*256 + threadIdx.x;
  if (idx < n){
    int r = rp[idx] + bsum[blockIdx.x];
    rp[idx] = r; cur[idx] = r;
    dinv_o[idx] = rsqrtf((float)(cnt[idx] + 1));
  }
  if (idx == 0) rp[n] = e;
}

__global__ void k_scatter(const int* __restrict__ src, const int* __restrict__ dst,
                          const float* __restrict__ sc, int* __restrict__ cur,
                          int* __restrict__ col, float* __restrict__ wsrt, int e){
  int i = blockIdx.x*256 + threadIdx.x;
  if (i >= e) return;
  int d = dst[i];
  int p = atomicAdd(&cur[d], 1);
  col[p] = src[i];
  wsrt[p] = sc[i];
}

__global__ void k_deg(const int* __restrict__ rp, const float* __restrict__ wsrt,
                      float* __restrict__ dinv_s, int n){
  int i = blockIdx.x*256 + threadIdx.x;
  if (i >= n) return;
  float s = 1.0f;
  int e0 = rp[i], e1 = rp[i+1];
  for (int j = e0; j < e1; ++j) s += wsrt[j];
  dinv_s[i] = rsqrtf(s);
}

// ---------------- weight convert: fp32 W[k][col] -> bf16 Wt[col][k], 6 mats ----
__global__ void k_wconv(const float* __restrict__ W0, const float* __restrict__ W1,
                        const float* __restrict__ W2, const float* __restrict__ W3,
                        const float* __restrict__ W4, const float* __restrict__ W5,
                        u16* __restrict__ wt){
  const float* Ws[6] = {W0,W1,W2,W3,W4,W5};
  const float* W = Ws[blockIdx.y];
  u16* Wt = wt + (size_t)blockIdx.y*16384;
  int idx = blockIdx.x*256 + threadIdx.x;          // = k*128 + col
  int k = idx >> 7, col = idx & 127;
  Wt[col*128 + k] = f2bf(W[idx]);
}

// ---------------- aggregations: one wave per node ----------------
__global__ __launch_bounds__(256) void k_agg_dual(
    const float* __restrict__ x, const int* __restrict__ rp,
    const int* __restrict__ col, const float* __restrict__ wsrt,
    const float* __restrict__ dinv_s, const float* __restrict__ dinv_o,
    u16* __restrict__ out_s, u16* __restrict__ out_o, int n){
  int wid = (blockIdx.x * 256 + threadIdx.x) >> 6;
  int lane = threadIdx.x & 63;
  if (wid >= n) return;
  const float2* x2 = (const float2*)x;
  float dsv = dinv_s[wid], dov = dinv_o[wid];
  float2 xv = x2[(size_t)wid*64 + lane];
  float ss = dsv*dsv, oo = dov*dov;
  float2 as = { xv.x*ss, xv.y*ss };
  float2 ao = { xv.x*oo, xv.y*oo };
  int e0 = rp[wid], e1 = rp[wid+1];
  for (int base = e0; base < e1; base += 64){
    int cnt = e1 - base; if (cnt > 64) cnt = 64;
    int idx = base + (lane < cnt ? lane : cnt - 1);
    int   sl = col[idx];
    float wl = wsrt[idx];
    float nsl = dinv_s[sl] * wl * dsv;
    float nol = dinv_o[sl] * dov;
    int j = 0;
    for (; j + 4 <= cnt; j += 4){
      int   s0=__shfl(sl,j),   s1=__shfl(sl,j+1),   s2=__shfl(sl,j+2),   s3=__shfl(sl,j+3);
      float a0=__shfl(nsl,j),  a1=__shfl(nsl,j+1),  a2=__shfl(nsl,j+2),  a3=__shfl(nsl,j+3);
      float b0=__shfl(nol,j),  b1=__shfl(nol,j+1),  b2=__shfl(nol,j+2),  b3=__shfl(nol,j+3);
      float2 r0 = x2[(size_t)s0*64 + lane];
      float2 r1 = x2[(size_t)s1*64 + lane];
      float2 r2 = x2[(size_t)s2*64 + lane];
      float2 r3 = x2[(size_t)s3*64 + lane];
      as.x = fmaf(a0,r0.x,as.x); as.y = fmaf(a0,r0.y,as.y);
      ao.x = fmaf(b0,r0.x,ao.x); ao.y = fmaf(b0,r0.y,ao.y);
      as.x = fmaf(a1,r1.x,as.x); as.y = fmaf(a1,r1.y,as.y);
      ao.x = fmaf(b1,r1.x,ao.x); ao.y = fmaf(b1,r1.y,ao.y);
      as.x = fmaf(a2,r2.x,as.x); as.y = fmaf(a2,r2.y,as.y);
      ao.x = fmaf(b2,r2.x,ao.x); ao.y = fmaf(b2,r2.y,ao.y);
      as.x = fmaf(a3,r3.x,as.x); as.y = fmaf(a3,r3.y,as.y);
      ao.x = fmaf(b3,r3.x,ao.x); ao.y = fmaf(b3,r3.y,ao.y);
    }
    for (; j < cnt; ++j){
      int   s0=__shfl(sl,j);
      float a0=__shfl(nsl,j), b0=__shfl(nol,j);
      float2 r0 = x2[(size_t)s0*64 + lane];
      as.x = fmaf(a0,r0.x,as.x); as.y = fmaf(a0,r0.y,as.y);
      ao.x = fmaf(b0,r0.x,ao.x); ao.y = fmaf(b0,r0.y,ao.y);
    }
  }
  ((u32*)out_s)[(size_t)wid*64 + lane] = (u32)f2bf(as.x) | ((u32)f2bf(as.y) << 16);
  ((u32*)out_o)[(size_t)wid*64 + lane] = (u32)f2bf(ao.x) | ((u32)f2bf(ao.y) << 16);
}

// bf16 gather input (enc_t), bf16 output
__global__ __launch_bounds__(256) void k_agg_one(
    const u16* __restrict__ h, const int* __restrict__ rp,
    const int* __restrict__ col, const float* __restrict__ dinv_o,
    u16* __restrict__ out, int n){
  int wid = (blockIdx.x * 256 + threadIdx.x) >> 6;
  int lane = threadIdx.x & 63;
  if (wid >= n) return;
  const u32* h2 = (const u32*)h;
  float dov = dinv_o[wid];
  u32 hv = h2[(size_t)wid*64 + lane];
  float oo = dov*dov;
  float2 ao = { bf2f((u16)(hv & 0xffff))*oo, bf2f((u16)(hv >> 16))*oo };
  int e0 = rp[wid], e1 = rp[wid+1];
  for (int base = e0; base < e1; base += 64){
    int cnt = e1 - base; if (cnt > 64) cnt = 64;
    int idx = base + (lane < cnt ? lane : cnt - 1);
    int   sl = col[idx];
    float nol = dinv_o[sl] * dov;
    int j = 0;
    for (; j + 4 <= cnt; j += 4){
      int   s0=__shfl(sl,j),  s1=__shfl(sl,j+1),  s2=__shfl(sl,j+2),  s3=__shfl(sl,j+3);
      float b0=__shfl(nol,j), b1=__shfl(nol,j+1), b2=__shfl(nol,j+2), b3=__shfl(nol,j+3);
      u32 r0 = h2[(size_t)s0*64 + lane];
      u32 r1 = h2[(size_t)s1*64 + lane];
      u32 r2 = h2[(size_t)s2*64 + lane];
      u32 r3 = h2[(size_t)s3*64 + lane];
      ao.x = fmaf(b0, bf2f((u16)(r0&0xffff)), ao.x); ao.y = fmaf(b0, bf2f((u16)(r0>>16)), ao.y);
      ao.x = fmaf(b1, bf2f((u16)(r1&0xffff)), ao.x); ao.y = fmaf(b1, bf2f((u16)(r1>>16)), ao.y);
      ao.x = fmaf(b2, bf2f((u16)(r2&0xffff)), ao.x); ao.y = fmaf(b2, bf2f((u16)(r2>>16)), ao.y);
      ao.x = fmaf(b3, bf2f((u16)(r3&0xffff)), ao.x); ao.y = fmaf(b3, bf2f((u16)(r3>>16)), ao.y);
    }
    for (; j < cnt; ++j){
      int   s0=__shfl(sl,j);
      float b0=__shfl(nol,j);
      u32 r0 = h2[(size_t)s0*64 + lane];
      ao.x = fmaf(b0, bf2f((u16)(r0&0xffff)), ao.x); ao.y = fmaf(b0, bf2f((u16)(r0>>16)), ao.y);
    }
  }
  ((u32*)out)[(size_t)wid*64 + lane] = (u32)f2bf(ao.x) | ((u32)f2bf(ao.y) << 16);
}

// ---------------- MFMA GEMMs: ZERO-LDS, fragments direct from global ----------
// W (32 KB, shared by every block) stays L2/L1-hot; A rows read exactly once —
// LDS staging was pure overhead (R8: occupancy 20%, all pipes idle).
// Frags (16x16x32): A row=lane&15, k=(lane>>4)*8+j ; B col=lane&15 (Wt[col][k]);
// C/D col=lane&15, row=(lane>>4)*4+reg  [verified R8 pass].
// Each of 4 waves owns 16 rows; no barriers in the GEMM.

__global__ __launch_bounds__(256) void k_mfma_act2(
    const u16* __restrict__ A0, const u16* __restrict__ Wt0, const float* __restrict__ b0,
    const u16* __restrict__ A1, const u16* __restrict__ Wt1, const float* __restrict__ b1,
    const float* __restrict__ temb, const int* __restrict__ t_ptr,
    u16* __restrict__ out0, u16* __restrict__ out1, int n){
  const int sl = blockIdx.y;
  const u16* A  = sl ? A1 : A0;
  const u16* Wt = sl ? Wt1 : Wt0;
  const float* b = sl ? b1 : b0;
  u16* out = sl ? out1 : out0;
  const int tid = threadIdx.x;
  const int lane = tid & 63, wave = tid >> 6;
  const int lr = lane & 15, lg = lane >> 4;
  const int row0 = blockIdx.x * 64;
  int rowf = row0 + wave*16 + lr;
  int rowc = rowf < n ? rowf : n - 1;
  const char* Arow = (const char*)A + (size_t)rowc*256;
  const char* Wb   = (const char*)Wt + lg*16;
  f32x4 z = {0.f,0.f,0.f,0.f};
  f32x4 acc[8];
  #pragma unroll
  for (int i = 0; i < 8; ++i) acc[i] = z;
  #pragma unroll
  for (int ks = 0; ks < 4; ++ks){
    bf16x8 a = *(const bf16x8*)(Arow + ks*64 + lg*16);
    #pragma unroll
    for (int cf = 0; cf < 8; ++cf){
      bf16x8 bb = *(const bf16x8*)(Wb + (cf*16 + lr)*256 + ks*64);
      acc[cf] = __builtin_amdgcn_mfma_f32_16x16x32_bf16(a, bb, acc[cf], 0, 0, 0);
    }
  }
  int t = sl ? *t_ptr : 0;
  int rbase = row0 + wave*16 + (lg << 2);
  #pragma unroll
  for (int cf = 0; cf < 8; ++cf){
    int colw = cf*16 + lr;
    float bb = b[colw];
    float tt = sl ? temb[t*128 + colw] : 0.f;
    #pragma unroll
    for (int r = 0; r < 4; ++r){
      int row = rbase + r;
      if (row < n)
        out[(size_t)row*128 + colw] = f2bf(fmaxf(acc[cf][r] + bb, 0.f) + tt);
    }
  }
}

// dual: pm = A@W1+b1 (linear), ps = sigmoid(A@W2+b2); packed u32 output (pm|ps<<16)
__global__ __launch_bounds__(256) void k_mfma_dual(
    const u16* __restrict__ A, const u16* __restrict__ Wt1, const float* __restrict__ b1,
    const u16* __restrict__ Wt2, const float* __restrict__ b2,
    u32* __restrict__ pmps, int n){
  const int tid = threadIdx.x;
  const int lane = tid & 63, wave = tid >> 6;
  const int lr = lane & 15, lg = lane >> 4;
  const int row0 = blockIdx.x * 64;
  int rowf = row0 + wave*16 + lr;
  int rowc = rowf < n ? rowf : n - 1;
  const char* Arow = (const char*)A + (size_t)rowc*256;
  const char* W1b  = (const char*)Wt1 + lg*16;
  const char* W2b  = (const char*)Wt2 + lg*16;
  f32x4 z = {0.f,0.f,0.f,0.f};
  f32x4 acc1[8], acc2[8];
  #pragma unroll
  for (int i = 0; i < 8; ++i){ acc1[i] = z; acc2[i] = z; }
  #pragma unroll
  for (int ks = 0; ks < 4; ++ks){
    bf16x8 a = *(const bf16x8*)(Arow + ks*64 + lg*16);
    #pragma unroll
    for (int cf = 0; cf < 8; ++cf){
      int off = (cf*16 + lr)*256 + ks*64;
      bf16x8 bb1 = *(const bf16x8*)(W1b + off);
      acc1[cf] = __builtin_amdgcn_mfma_f32_16x16x32_bf16(a, bb1, acc1[cf], 0, 0, 0);
      bf16x8 bb2 = *(const bf16x8*)(W2b + off);
      acc2[cf] = __builtin_amdgcn_mfma_f32_16x16x32_bf16(a, bb2, acc2[cf], 0, 0, 0);
    }
  }
  int rbase = row0 + wave*16 + (lg << 2);
  #pragma unroll
  for (int cf = 0; cf < 8; ++cf){
    int colw = cf*16 + lr;
    float bb1 = b1[colw], bb2 = b2[colw];
    #pragma unroll
    for (int r = 0; r < 4; ++r){
      int row = rbase + r;
      if (row < n){
        u16 pmh = f2bf(acc1[cf][r] + bb1);
        u16 psh = f2bf(sigmoidf_(acc2[cf][r] + bb2));
        pmps[(size_t)row*128 + colw] = (u32)pmh | ((u32)psh << 16);
      }
    }
  }
}

// final: em = A@Wmu+bmu, es = sigmoid(A@Wstd+bstd); conf = eps*es+em (fp32 out);
// kl partials -> pblk
__global__ __launch_bounds__(256) void k_mfma_final(
    const u16* __restrict__ A, const u16* __restrict__ Wtmu, const float* __restrict__ bmu,
    const u16* __restrict__ Wtstd, const float* __restrict__ bstd,
    const u32* __restrict__ pmps,
    float* __restrict__ conf, float* __restrict__ pblk, int n){
  const int tid = threadIdx.x;
  const int lane = tid & 63, wave = tid >> 6;
  const int lr = lane & 15, lg = lane >> 4;
  const int row0 = blockIdx.x * 64;
  int rowf = row0 + wave*16 + lr;
  int rowc = rowf < n ? rowf : n - 1;
  const char* Arow = (const char*)A + (size_t)rowc*256;
  const char* W1b  = (const char*)Wtmu + lg*16;
  const char* W2b  = (const char*)Wtstd + lg*16;
  f32x4 z = {0.f,0.f,0.f,0.f};
  f32x4 acc1[8], acc2[8];
  #pragma unroll
  for (int i = 0; i < 8; ++i){ acc1[i] = z; acc2[i] = z; }
  #pragma unroll
  for (int ks = 0; ks < 4; ++ks){
    bf16x8 a = *(const bf16x8*)(Arow + ks*64 + lg*16);
    #pragma unroll
    for (int cf = 0; cf < 8; ++cf){
      int off = (cf*16 + lr)*256 + ks*64;
      bf16x8 bb1 = *(const bf16x8*)(W1b + off);
      acc1[cf] = __builtin_amdgcn_mfma_f32_16x16x32_bf16(a, bb1, acc1[cf], 0, 0, 0);
      bf16x8 bb2 = *(const bf16x8*)(W2b + off);
      acc2[cf] = __builtin_amdgcn_mfma_f32_16x16x32_bf16(a, bb2, acc2[cf], 0, 0, 0);
    }
  }
  const float EPS = 1e-9f;
  int rbase = row0 + wave*16 + (lg << 2);
  float klsum = 0.f;
  #pragma unroll
  for (int cf = 0; cf < 8; ++cf){
    int colw = cf*16 + lr;
    float bb1 = bmu[colw], bb2 = bstd[colw];
    #pragma unroll
    for (int r = 0; r < 4; ++r){
      int row = rbase + r;
      if (row < n){
        size_t m = (size_t)row*128 + colw;
        float em = acc1[cf][r] + bb1;
        float es = sigmoidf_(acc2[cf][r] + bb2);
        float eps = jax_normal_part_xor((u32)m);
        conf[m] = fmaf(eps, es, em);
        u32 pp = pmps[m];
        float pmv = bf2f((u16)(pp & 0xffff)), psv = bf2f((u16)(pp >> 16));
        float es_e = es + EPS, ps_e = psv + EPS;
        float diff = em - pmv;
        klsum += 2.0f*__logf(ps_e/es_e)
               + (es_e*es_e + diff*diff) / (ps_e*ps_e) - 1.0f;
      }
    }
  }
  #pragma unroll
  for (int off = 32; off > 0; off >>= 1) klsum += __shfl_down(klsum, off);
  __shared__ float wsum[4];
  if ((tid & 63) == 0) wsum[tid >> 6] = klsum;
  __syncthreads();
  if (tid == 0) pblk[blockIdx.x] = wsum[0] + wsum[1] + wsum[2] + wsum[3];
}

__global__ __launch_bounds__(256) void k_finish(const float* __restrict__ pblk, int nb,
                                                float* __restrict__ out0, int n){
  __shared__ double sh[256];
  double s = 0.0;
  for (int i = threadIdx.x; i < nb; i += 256) s += (double)pblk[i];
  sh[threadIdx.x] = s; __syncthreads();
  for (int off = 128; off > 0; off >>= 1){
    if (threadIdx.x < off) sh[threadIdx.x] += sh[threadIdx.x + off];
    __syncthreads();
  }
  if (threadIdx.x == 0) out0[0] = (float)(0.5 * sh[0] / (double)n);
}

// ---------------------------------------------------------------------------
extern "C" void kernel_launch(void* const* d_in, const int* in_sizes, int n_in,
                              void* d_out, int out_size, void* d_ws, size_t ws_size,
                              hipStream_t stream){
  const void*  eidx   = d_in[0];
  const float* x      = (const float*)d_in[1];
  const int*   t_ptr  = (const int*)d_in[2];
  const float* escore = (const float*)d_in[3];
  const float* W_enc = (const float*)d_in[6];  const float* b_enc = (const float*)d_in[7];
  const float* W_mu  = (const float*)d_in[8];  const float* b_mu  = (const float*)d_in[9];
  const float* W_std = (const float*)d_in[10]; const float* b_std = (const float*)d_in[11];
  const float* W_pr  = (const float*)d_in[12]; const float* b_pr  = (const float*)d_in[13];
  const float* W_pm  = (const float*)d_in[14]; const float* b_pm  = (const float*)d_in[15];
  const float* W_ps  = (const float*)d_in[16]; const float* b_ps  = (const float*)d_in[17];
  const float* temb  = (const float*)d_in[18];

  const int N = in_sizes[1] / D;
  const int E = in_sizes[3];

  char* w = (char*)d_ws;
  auto alloc = [&](size_t bytes) -> char* {
    char* p = w; w += (bytes + 255) & ~(size_t)255; return p;
  };
  int*    flag   = (int*)   alloc(256);
  int*    src_w  = (int*)   alloc((size_t)E*4);
  int*    dst_w  = (int*)   alloc((size_t)E*4);
  int*    cnt    = (int*)   alloc((size_t)N*4);
  int*    rp     = (int*)   alloc((size_t)(N+1)*4);
  int*    cur    = (int*)   alloc((size_t)N*4);
  float*  dinv_s = (float*) alloc((size_t)N*4);
  float*  dinv_o = (float*) alloc((size_t)N*4);
  int*    bsum   = (int*)   alloc(1024*4);
  int*    col    = (int*)   alloc((size_t)E*4);
  float*  wsrt   = (float*) alloc((size_t)E*4);
  u16*    wt     = (u16*)   alloc((size_t)6*16384*2);  // 6 transposed bf16 weights
  u16*    B1     = (u16*)   alloc((size_t)N*D*2);  // agg_score_x (bf16)
  u16*    B2     = (u16*)   alloc((size_t)N*D*2);  // agg_ones_x -> agg_ones_enc
  u16*    B3     = (u16*)   alloc((size_t)N*D*2);  // enc_t
  u32*    PMPS   = (u32*)   alloc((size_t)N*D*4);  // packed pm|ps
  u16*    B5     = (u16*)   alloc((size_t)N*D*2);  // prior
  const int gG64 = (N + 63) / 64;                  // MFMA tiles (64 rows)
  float*  pblk   = (float*) alloc((size_t)gG64*4);
  (void)ws_size; (void)n_in; (void)out_size;

  float* conf = ((float*)d_out) + 1;

  u16* Wt_enc = wt + 0*16384;
  u16* Wt_pr  = wt + 1*16384;
  u16* Wt_pm  = wt + 2*16384;
  u16* Wt_ps  = wt + 3*16384;
  u16* Wt_mu  = wt + 4*16384;
  u16* Wt_std = wt + 5*16384;

  const int gE  = (E + 255) / 256;
  const int gN  = (N + 255) / 256;
  const int gW  = (N * 64 + 255) / 256;

  k_wconv <<<dim3(64,6), 256, 0, stream>>>(W_enc, W_pr, W_pm, W_ps, W_mu, W_std, wt);
  k_detect <<<1, 256, 0, stream>>>((const u32*)eidx, flag);
  k_norm   <<<gE, 256, 0, stream>>>(eidx, flag, src_w, dst_w, E);
  k_init   <<<gN, 256, 0, stream>>>(cnt, N);
  k_hist   <<<gE, 256, 0, stream>>>(dst_w, cnt, E);
  k_scan1  <<<gN, 256, 0, stream>>>(cnt, rp, bsum, N);
  k_scan2  <<<1, 1024, 0, stream>>>(bsum, gN);
  k_scan3  <<<gN, 256, 0, stream>>>(rp, cur, bsum, cnt, dinv_o, N, E);
  k_scatter<<<gE, 256, 0, stream>>>(src_w, dst_w, escore, cur, col, wsrt, E);
  k_deg    <<<gN, 256, 0, stream>>>(rp, wsrt, dinv_s, N);

  // agg_sx -> B1 (bf16) ; agg_ox -> B2 (bf16)
  k_agg_dual<<<gW, 256, 0, stream>>>(x, rp, col, wsrt, dinv_s, dinv_o, B1, B2, N);
  // y=0: enc_t = relu(B1@Wenc+b) -> B3 ; y=1: prior = relu(B2@Wpr+b)+temb -> B5
  k_mfma_act2<<<dim3(gG64,2), 256, 0, stream>>>(B1, Wt_enc, b_enc, B2, Wt_pr, b_pr,
                                                temb, t_ptr, B3, B5, N);
  // agg_oe = A_ones enc_t -> B2 (bf16 gather)
  k_agg_one<<<gW, 256, 0, stream>>>(B3, rp, col, dinv_o, B2, N);
  // pm|ps packed -> PMPS
  k_mfma_dual<<<gG64, 256, 0, stream>>>(B5, Wt_pm, b_pm, Wt_ps, b_ps, PMPS, N);
  // em/es + conf + kl partials
  k_mfma_final<<<gG64, 256, 0, stream>>>(B2, Wt_mu, b_mu, Wt_std, b_std, PMPS,
                                         conf, pblk, N);
  k_finish<<<1, 256, 0, stream>>>(pblk, gG64, (float*)d_out, N);
}

// Round 10
// 337.744 us; speedup vs baseline: 1.7854x; 1.1379x over previous
//
#include <hip/hip_runtime.h>
#include <math.h>

#define D 128

typedef unsigned int u32;
typedef unsigned short u16;
typedef __attribute__((ext_vector_type(8))) short bf16x8;   // 8 bf16 (4 VGPRs)
typedef __attribute__((ext_vector_type(4))) float f32x4;    // MFMA C/D
typedef __attribute__((ext_vector_type(4))) u32 u32x4;

__device__ __forceinline__ u32 rotl32(u32 x, int r){ return (x<<r) | (x>>(32-r)); }

__device__ __forceinline__ u16 f2bf(float x){                // round-to-nearest-even
  u32 u = __float_as_uint(x);
  return (u16)((u + 0x7fffu + ((u >> 16) & 1u)) >> 16);
}
__device__ __forceinline__ float bf2f(u16 h){ return __uint_as_float(((u32)h) << 16); }

// eps = jax.random.normal(jax.random.key(42), ...), element m (row-major flat).
// Threefry PARTITIONABLE: counter (0,m), key (0,42); bits = x0^x1.  [verified R3]
__device__ __forceinline__ float jax_normal_part_xor(u32 m){
  const u32 ks0 = 0u, ks1 = 42u, ks2 = 0x1BD11BF0u;
  u32 x0 = 0u + ks0;
  u32 x1 = m  + ks1;
  #define TF_R4(a,b,c,d) \
    x0 += x1; x1 = rotl32(x1,(a)); x1 ^= x0; \
    x0 += x1; x1 = rotl32(x1,(b)); x1 ^= x0; \
    x0 += x1; x1 = rotl32(x1,(c)); x1 ^= x0; \
    x0 += x1; x1 = rotl32(x1,(d)); x1 ^= x0;
  TF_R4(13,15,26,6)   x0 += ks1; x1 += ks2 + 1u;
  TF_R4(17,29,16,24)  x0 += ks2; x1 += ks0 + 2u;
  TF_R4(13,15,26,6)   x0 += ks0; x1 += ks1 + 3u;
  TF_R4(17,29,16,24)  x0 += ks1; x1 += ks2 + 4u;
  TF_R4(13,15,26,6)   x0 += ks2; x1 += ks0 + 5u;
  #undef TF_R4
  u32 bits = x0 ^ x1;
  float f = __uint_as_float((bits >> 9) | 0x3F800000u) - 1.0f;
  const float LO = -0.99999994f;
  float u = fmaxf(LO, f * 2.0f + LO);
  float w = -__logf(fmaf(-u, u, 1.0f));       // = -log(1-u^2)
  float p;
  if (w < 5.0f){
    w -= 2.5f;
    p =  2.81022636e-08f;
    p = fmaf(p, w,  3.43273939e-07f);
    p = fmaf(p, w, -3.5233877e-06f);
    p = fmaf(p, w, -4.39150654e-06f);
    p = fmaf(p, w,  0.00021858087f);
    p = fmaf(p, w, -0.00125372503f);
    p = fmaf(p, w, -0.00417768164f);
    p = fmaf(p, w,  0.246640727f);
    p = fmaf(p, w,  1.50140941f);
  } else {
    w = sqrtf(w) - 3.0f;
    p = -0.000200214257f;
    p = fmaf(p, w,  0.000100950558f);
    p = fmaf(p, w,  0.00134934322f);
    p = fmaf(p, w, -0.00367342844f);
    p = fmaf(p, w,  0.00573950773f);
    p = fmaf(p, w, -0.0076224613f);
    p = fmaf(p, w,  0.00943887047f);
    p = fmaf(p, w,  1.00167406f);
    p = fmaf(p, w,  2.83297682f);
  }
  return 1.41421354f * (p * u);
}

__device__ __forceinline__ float sigmoidf_(float z){ return 1.0f / (1.0f + __expf(-z)); }

// ---------------- eps pregen: grid-stride, full occupancy, bf16-packed --------
__global__ __launch_bounds__(256) void k_eps(u32* __restrict__ epsb, int half_total){
  int idx = blockIdx.x*256 + threadIdx.x;
  int stride = gridDim.x*256;
  for (int i = idx; i < half_total; i += stride){
    u32 m0 = 2u*(u32)i;
    float e0 = jax_normal_part_xor(m0);
    float e1 = jax_normal_part_xor(m0 + 1u);
    epsb[i] = (u32)f2bf(e0) | ((u32)f2bf(e1) << 16);
  }
}

// ---------------- index normalization ----------------
__global__ void k_detect(const u32* __restrict__ e_u32, int* __restrict__ flag){
  __shared__ int s_nz;
  if (threadIdx.x == 0) s_nz = 0;
  __syncthreads();
  if (e_u32[2*threadIdx.x + 1] != 0u) atomicAdd(&s_nz, 1);
  __syncthreads();
  if (threadIdx.x == 0) *flag = (s_nz == 0) ? 1 : 0;
}

__global__ void k_norm(const void* __restrict__ eidx, const int* __restrict__ flag,
                       int* __restrict__ src_w, int* __restrict__ dst_w, int e){
  int i = blockIdx.x*256 + threadIdx.x;
  if (i >= e) return;
  if (*flag){
    const u32* u = (const u32*)eidx;
    src_w[i] = (int)u[2*(size_t)i];
    dst_w[i] = (int)u[2*((size_t)e + i)];
  } else {
    const int* p = (const int*)eidx;
    src_w[i] = p[i];
    dst_w[i] = p[e + i];
  }
}

// ---------------- CSR build (int atomics only) ----------------
__global__ void k_init(int* __restrict__ cnt, int n){
  int i = blockIdx.x*256 + threadIdx.x;
  if (i < n) cnt[i] = 0;
}

__global__ void k_hist(const int* __restrict__ dst, int* __restrict__ cnt, int e){
  int i = blockIdx.x*256 + threadIdx.x;
  if (i >= e) return;
  atomicAdd(&cnt[dst[i]], 1);
}

__global__ __launch_bounds__(256) void k_scan1(const int* __restrict__ cnt,
                                               int* __restrict__ rp,
                                               int* __restrict__ bsum, int n){
  __shared__ int sh[256];
  int tid = threadIdx.x, idx = blockIdx.x*256 + tid;
  int v = (idx < n) ? cnt[idx] : 0;
  sh[tid] = v; __syncthreads();
  for (int off = 1; off < 256; off <<= 1){
    int t = (tid >= off) ? sh[tid-off] : 0;
    __syncthreads(); sh[tid] += t; __syncthreads();
  }
  if (idx < n) rp[idx] = sh[tid] - v;
  if (tid == 255) bsum[blockIdx.x] = sh[255];
}

__global__ __launch_bounds__(1024) void k_scan2(int* __restrict__ bsum, int nb){
  __shared__ int sh[1024];
  int tid = threadIdx.x;
  int v = (tid < nb) ? bsum[tid] : 0;
  sh[tid] = v; __syncthreads();
  for (int off = 1; off < 1024; off <<= 1){
    int t = (tid >= off) ? sh[tid-off] : 0;
    __syncthreads(); sh[tid] += t; __syncthreads();
  }
  if (tid < nb) bsum[tid] = sh[tid] - v;
}

__global__ void k_scan3(int* __restrict__ rp, int* __restrict__ cur,
                        const int* __restrict__ bsum, const int* __restrict__ cnt,
                        float* __restrict__ dinv_o, int n, int e){
  int idx = blockIdx.x*256 + threadIdx.x;
  if (idx < n){
    int r = rp[idx] + bsum[blockIdx.x];
    rp[idx] = r; cur[idx] = r;
    dinv_o[idx] = rsqrtf((float)(cnt[idx] + 1));
  }
  if (idx == 0) rp[n] = e;
}

__global__ void k_scatter(const int* __restrict__ src, const int* __restrict__ dst,
                          const float* __restrict__ sc, int* __restrict__ cur,
                          int* __restrict__ col, float* __restrict__ wsrt, int e){
  int i = blockIdx.x*256 + threadIdx.x;
  if (i >= e) return;
  int d = dst[i];
  int p = atomicAdd(&cur[d], 1);
  col[p] = src[i];
  wsrt[p] = sc[i];
}

__global__ void k_deg(const int* __restrict__ rp, const float* __restrict__ wsrt,
                      float* __restrict__ dinv_s, int n){
  int i = blockIdx.x*256 + threadIdx.x;
  if (i >= n) return;
  float s = 1.0f;
  int e0 = rp[i], e1 = rp[i+1];
  for (int j = e0; j < e1; ++j) s += wsrt[j];
  dinv_s[i] = rsqrtf(s);
}

// ---------------- weight convert: fp32 W[k][col] -> bf16 Wt[col][k], 6 mats ----
__global__ void k_wconv(const float* __restrict__ W0, const float* __restrict__ W1,
                        const float* __restrict__ W2, const float* __restrict__ W3,
                        const float* __restrict__ W4, const float* __restrict__ W5,
                        u16* __restrict__ wt){
  const float* Ws[6] = {W0,W1,W2,W3,W4,W5};
  const float* W = Ws[blockIdx.y];
  u16* Wt = wt + (size_t)blockIdx.y*16384;
  int idx = blockIdx.x*256 + threadIdx.x;          // = k*128 + col
  int k = idx >> 7, col = idx & 127;
  Wt[col*128 + k] = f2bf(W[idx]);
}

// ---------------- aggregations: one wave per node ----------------
__global__ __launch_bounds__(256) void k_agg_dual(
    const float* __restrict__ x, const int* __restrict__ rp,
    const int* __restrict__ col, const float* __restrict__ wsrt,
    const float* __restrict__ dinv_s, const float* __restrict__ dinv_o,
    u16* __restrict__ out_s, u16* __restrict__ out_o, int n){
  int wid = (blockIdx.x * 256 + threadIdx.x) >> 6;
  int lane = threadIdx.x & 63;
  if (wid >= n) return;
  const float2* x2 = (const float2*)x;
  float dsv = dinv_s[wid], dov = dinv_o[wid];
  float2 xv = x2[(size_t)wid*64 + lane];
  float ss = dsv*dsv, oo = dov*dov;
  float2 as = { xv.x*ss, xv.y*ss };
  float2 ao = { xv.x*oo, xv.y*oo };
  int e0 = rp[wid], e1 = rp[wid+1];
  for (int base = e0; base < e1; base += 64){
    int cnt = e1 - base; if (cnt > 64) cnt = 64;
    int idx = base + (lane < cnt ? lane : cnt - 1);
    int   sl = col[idx];
    float wl = wsrt[idx];
    float nsl = dinv_s[sl] * wl * dsv;
    float nol = dinv_o[sl] * dov;
    int j = 0;
    for (; j + 4 <= cnt; j += 4){
      int   s0=__shfl(sl,j),   s1=__shfl(sl,j+1),   s2=__shfl(sl,j+2),   s3=__shfl(sl,j+3);
      float a0=__shfl(nsl,j),  a1=__shfl(nsl,j+1),  a2=__shfl(nsl,j+2),  a3=__shfl(nsl,j+3);
      float b0=__shfl(nol,j),  b1=__shfl(nol,j+1),  b2=__shfl(nol,j+2),  b3=__shfl(nol,j+3);
      float2 r0 = x2[(size_t)s0*64 + lane];
      float2 r1 = x2[(size_t)s1*64 + lane];
      float2 r2 = x2[(size_t)s2*64 + lane];
      float2 r3 = x2[(size_t)s3*64 + lane];
      as.x = fmaf(a0,r0.x,as.x); as.y = fmaf(a0,r0.y,as.y);
      ao.x = fmaf(b0,r0.x,ao.x); ao.y = fmaf(b0,r0.y,ao.y);
      as.x = fmaf(a1,r1.x,as.x); as.y = fmaf(a1,r1.y,as.y);
      ao.x = fmaf(b1,r1.x,ao.x); ao.y = fmaf(b1,r1.y,ao.y);
      as.x = fmaf(a2,r2.x,as.x); as.y = fmaf(a2,r2.y,as.y);
      ao.x = fmaf(b2,r2.x,ao.x); ao.y = fmaf(b2,r2.y,ao.y);
      as.x = fmaf(a3,r3.x,as.x); as.y = fmaf(a3,r3.y,as.y);
      ao.x = fmaf(b3,r3.x,ao.x); ao.y = fmaf(b3,r3.y,ao.y);
    }
    for (; j < cnt; ++j){
      int   s0=__shfl(sl,j);
      float a0=__shfl(nsl,j), b0=__shfl(nol,j);
      float2 r0 = x2[(size_t)s0*64 + lane];
      as.x = fmaf(a0,r0.x,as.x); as.y = fmaf(a0,r0.y,as.y);
      ao.x = fmaf(b0,r0.x,ao.x); ao.y = fmaf(b0,r0.y,ao.y);
    }
  }
  ((u32*)out_s)[(size_t)wid*64 + lane] = (u32)f2bf(as.x) | ((u32)f2bf(as.y) << 16);
  ((u32*)out_o)[(size_t)wid*64 + lane] = (u32)f2bf(ao.x) | ((u32)f2bf(ao.y) << 16);
}

// bf16 gather input (enc_t), bf16 output
__global__ __launch_bounds__(256) void k_agg_one(
    const u16* __restrict__ h, const int* __restrict__ rp,
    const int* __restrict__ col, const float* __restrict__ dinv_o,
    u16* __restrict__ out, int n){
  int wid = (blockIdx.x * 256 + threadIdx.x) >> 6;
  int lane = threadIdx.x & 63;
  if (wid >= n) return;
  const u32* h2 = (const u32*)h;
  float dov = dinv_o[wid];
  u32 hv = h2[(size_t)wid*64 + lane];
  float oo = dov*dov;
  float2 ao = { bf2f((u16)(hv & 0xffff))*oo, bf2f((u16)(hv >> 16))*oo };
  int e0 = rp[wid], e1 = rp[wid+1];
  for (int base = e0; base < e1; base += 64){
    int cnt = e1 - base; if (cnt > 64) cnt = 64;
    int idx = base + (lane < cnt ? lane : cnt - 1);
    int   sl = col[idx];
    float nol = dinv_o[sl] * dov;
    int j = 0;
    for (; j + 4 <= cnt; j += 4){
      int   s0=__shfl(sl,j),  s1=__shfl(sl,j+1),  s2=__shfl(sl,j+2),  s3=__shfl(sl,j+3);
      float b0=__shfl(nol,j), b1=__shfl(nol,j+1), b2=__shfl(nol,j+2), b3=__shfl(nol,j+3);
      u32 r0 = h2[(size_t)s0*64 + lane];
      u32 r1 = h2[(size_t)s1*64 + lane];
      u32 r2 = h2[(size_t)s2*64 + lane];
      u32 r3 = h2[(size_t)s3*64 + lane];
      ao.x = fmaf(b0, bf2f((u16)(r0&0xffff)), ao.x); ao.y = fmaf(b0, bf2f((u16)(r0>>16)), ao.y);
      ao.x = fmaf(b1, bf2f((u16)(r1&0xffff)), ao.x); ao.y = fmaf(b1, bf2f((u16)(r1>>16)), ao.y);
      ao.x = fmaf(b2, bf2f((u16)(r2&0xffff)), ao.x); ao.y = fmaf(b2, bf2f((u16)(r2>>16)), ao.y);
      ao.x = fmaf(b3, bf2f((u16)(r3&0xffff)), ao.x); ao.y = fmaf(b3, bf2f((u16)(r3>>16)), ao.y);
    }
    for (; j < cnt; ++j){
      int   s0=__shfl(sl,j);
      float b0=__shfl(nol,j);
      u32 r0 = h2[(size_t)s0*64 + lane];
      ao.x = fmaf(b0, bf2f((u16)(r0&0xffff)), ao.x); ao.y = fmaf(b0, bf2f((u16)(r0>>16)), ao.y);
    }
  }
  ((u32*)out)[(size_t)wid*64 + lane] = (u32)f2bf(ao.x) | ((u32)f2bf(ao.y) << 16);
}

// ---------------- MFMA GEMMs: zero-LDS, split-N wave geometry ------------------
// Wave = 16 rows x 64 cols (4 col-fragments); block 256 thr = 4 waves covers
// 32 rows x 128 cols -> 1563 blocks, 6252 waves (~6/SIMD, 2x R9 latency hiding).
// Frags (16x16x32): A row=lane&15, k=(lane>>4)*8+j ; B col=lane&15 (Wt[col][k]);
// C/D col=lane&15, row=(lane>>4)*4+reg  [verified R8/R9 pass].

// y=0: out0 = relu(A0@W0+b0); y=1: out1 = relu(A1@W1+b1)+temb[t]
__global__ __launch_bounds__(256) void k_mfma_act2(
    const u16* __restrict__ A0, const u16* __restrict__ Wt0, const float* __restrict__ b0,
    const u16* __restrict__ A1, const u16* __restrict__ Wt1, const float* __restrict__ b1,
    const float* __restrict__ temb, const int* __restrict__ t_ptr,
    u16* __restrict__ out0, u16* __restrict__ out1, int n){
  const int sl = blockIdx.y;
  const u16* A  = sl ? A1 : A0;
  const u16* Wt = sl ? Wt1 : Wt0;
  const float* b = sl ? b1 : b0;
  u16* out = sl ? out1 : out0;
  const int tid = threadIdx.x;
  const int lane = tid & 63, wave = tid >> 6;
  const int lr = lane & 15, lg = lane >> 4;
  const int rw = wave >> 1, cw = wave & 1;
  const int row0 = blockIdx.x*32 + rw*16;
  int rowf = row0 + lr;
  int rowc = rowf < n ? rowf : n - 1;
  const char* Arow = (const char*)A + (size_t)rowc*256;
  const char* Wb   = (const char*)Wt + (cw*64 + lr)*256 + lg*16;
  f32x4 z = {0.f,0.f,0.f,0.f};
  f32x4 acc[4];
  #pragma unroll
  for (int i = 0; i < 4; ++i) acc[i] = z;
  #pragma unroll
  for (int ks = 0; ks < 4; ++ks){
    bf16x8 a = *(const bf16x8*)(Arow + ks*64 + lg*16);
    #pragma unroll
    for (int cf = 0; cf < 4; ++cf){
      bf16x8 bb = *(const bf16x8*)(Wb + cf*16*256 + ks*64);
      acc[cf] = __builtin_amdgcn_mfma_f32_16x16x32_bf16(a, bb, acc[cf], 0, 0, 0);
    }
  }
  int t = sl ? *t_ptr : 0;
  int rbase = row0 + (lg << 2);
  #pragma unroll
  for (int cf = 0; cf < 4; ++cf){
    int colw = cw*64 + cf*16 + lr;
    float bb = b[colw];
    float tt = sl ? temb[t*128 + colw] : 0.f;
    #pragma unroll
    for (int r = 0; r < 4; ++r){
      int row = rbase + r;
      if (row < n)
        out[(size_t)row*128 + colw] = f2bf(fmaxf(acc[cf][r] + bb, 0.f) + tt);
    }
  }
}

// quad: pm = Apr@Wpm+b (linear), ps = sig(Apr@Wps+b), em = Aen@Wmu+b,
// es = sig(Aen@Wsd+b); conf = eps*es+em; kl partials -> pblk. No pmps round-trip.
__global__ __launch_bounds__(256) void k_mfma_quad(
    const u16* __restrict__ Apr, const u16* __restrict__ Aen,
    const u16* __restrict__ Wtpm, const float* __restrict__ bpm,
    const u16* __restrict__ Wtps, const float* __restrict__ bps,
    const u16* __restrict__ Wtmu, const float* __restrict__ bmu,
    const u16* __restrict__ Wtsd, const float* __restrict__ bsd,
    const u32* __restrict__ epsb,
    float* __restrict__ conf, float* __restrict__ pblk, int n){
  const int tid = threadIdx.x;
  const int lane = tid & 63, wave = tid >> 6;
  const int lr = lane & 15, lg = lane >> 4;
  const int rw = wave >> 1, cw = wave & 1;
  const int row0 = blockIdx.x*32 + rw*16;
  int rowf = row0 + lr;
  int rowc = rowf < n ? rowf : n - 1;
  const char* Ap = (const char*)Apr + (size_t)rowc*256;
  const char* Ae = (const char*)Aen + (size_t)rowc*256;
  const int wcb = (cw*64 + lr)*256 + lg*16;
  const char* Wpm = (const char*)Wtpm + wcb;
  const char* Wps = (const char*)Wtps + wcb;
  const char* Wmu = (const char*)Wtmu + wcb;
  const char* Wsd = (const char*)Wtsd + wcb;
  f32x4 z = {0.f,0.f,0.f,0.f};
  f32x4 aPM[4], aPS[4], aMU[4], aSD[4];
  #pragma unroll
  for (int i = 0; i < 4; ++i){ aPM[i]=z; aPS[i]=z; aMU[i]=z; aSD[i]=z; }
  #pragma unroll
  for (int ks = 0; ks < 4; ++ks){
    bf16x8 a5 = *(const bf16x8*)(Ap + ks*64 + lg*16);
    bf16x8 a2 = *(const bf16x8*)(Ae + ks*64 + lg*16);
    #pragma unroll
    for (int cf = 0; cf < 4; ++cf){
      int off = cf*16*256 + ks*64;
      aPM[cf] = __builtin_amdgcn_mfma_f32_16x16x32_bf16(a5, *(const bf16x8*)(Wpm+off), aPM[cf], 0,0,0);
      aPS[cf] = __builtin_amdgcn_mfma_f32_16x16x32_bf16(a5, *(const bf16x8*)(Wps+off), aPS[cf], 0,0,0);
      aMU[cf] = __builtin_amdgcn_mfma_f32_16x16x32_bf16(a2, *(const bf16x8*)(Wmu+off), aMU[cf], 0,0,0);
      aSD[cf] = __builtin_amdgcn_mfma_f32_16x16x32_bf16(a2, *(const bf16x8*)(Wsd+off), aSD[cf], 0,0,0);
    }
  }
  const float EPS = 1e-9f;
  int rbase = row0 + (lg << 2);
  float klsum = 0.f;
  #pragma unroll
  for (int cf = 0; cf < 4; ++cf){
    int colw = cw*64 + cf*16 + lr;
    float bb1 = bpm[colw], bb2 = bps[colw];
    float bb3 = bmu[colw], bb4 = bsd[colw];
    #pragma unroll
    for (int r = 0; r < 4; ++r){
      int row = rbase + r;
      if (row < n){
        size_t m = (size_t)row*128 + colw;
        float pmv = aPM[cf][r] + bb1;
        float psv = sigmoidf_(aPS[cf][r] + bb2);
        float em  = aMU[cf][r] + bb3;
        float es  = sigmoidf_(aSD[cf][r] + bb4);
        u32 ew = epsb[m >> 1];
        float eps = bf2f((u16)((colw & 1) ? (ew >> 16) : (ew & 0xffff)));
        conf[m] = fmaf(eps, es, em);
        float es_e = es + EPS, ps_e = psv + EPS;
        float diff = em - pmv;
        klsum += 2.0f*__logf(ps_e/es_e)
               + (es_e*es_e + diff*diff) / (ps_e*ps_e) - 1.0f;
      }
    }
  }
  #pragma unroll
  for (int off = 32; off > 0; off >>= 1) klsum += __shfl_down(klsum, off);
  __shared__ float wsum[4];
  if ((tid & 63) == 0) wsum[tid >> 6] = klsum;
  __syncthreads();
  if (tid == 0) pblk[blockIdx.x] = wsum[0] + wsum[1] + wsum[2] + wsum[3];
}

__global__ __launch_bounds__(256) void k_finish(const float* __restrict__ pblk, int nb,
                                                float* __restrict__ out0, int n){
  __shared__ double sh[256];
  double s = 0.0;
  for (int i = threadIdx.x; i < nb; i += 256) s += (double)pblk[i];
  sh[threadIdx.x] = s; __syncthreads();
  for (int off = 128; off > 0; off >>= 1){
    if (threadIdx.x < off) sh[threadIdx.x] += sh[threadIdx.x + off];
    __syncthreads();
  }
  if (threadIdx.x == 0) out0[0] = (float)(0.5 * sh[0] / (double)n);
}

// ---------------------------------------------------------------------------
extern "C" void kernel_launch(void* const* d_in, const int* in_sizes, int n_in,
                              void* d_out, int out_size, void* d_ws, size_t ws_size,
                              hipStream_t stream){
  const void*  eidx   = d_in[0];
  const float* x      = (const float*)d_in[1];
  const int*   t_ptr  = (const int*)d_in[2];
  const float* escore = (const float*)d_in[3];
  const float* W_enc = (const float*)d_in[6];  const float* b_enc = (const float*)d_in[7];
  const float* W_mu  = (const float*)d_in[8];  const float* b_mu  = (const float*)d_in[9];
  const float* W_std = (const float*)d_in[10]; const float* b_std = (const float*)d_in[11];
  const float* W_pr  = (const float*)d_in[12]; const float* b_pr  = (const float*)d_in[13];
  const float* W_pm  = (const float*)d_in[14]; const float* b_pm  = (const float*)d_in[15];
  const float* W_ps  = (const float*)d_in[16]; const float* b_ps  = (const float*)d_in[17];
  const float* temb  = (const float*)d_in[18];

  const int N = in_sizes[1] / D;
  const int E = in_sizes[3];

  char* w = (char*)d_ws;
  auto alloc = [&](size_t bytes) -> char* {
    char* p = w; w += (bytes + 255) & ~(size_t)255; return p;
  };
  int*    flag   = (int*)   alloc(256);
  int*    src_w  = (int*)   alloc((size_t)E*4);
  int*    dst_w  = (int*)   alloc((size_t)E*4);
  int*    cnt    = (int*)   alloc((size_t)N*4);
  int*    rp     = (int*)   alloc((size_t)(N+1)*4);
  int*    cur    = (int*)   alloc((size_t)N*4);
  float*  dinv_s = (float*) alloc((size_t)N*4);
  float*  dinv_o = (float*) alloc((size_t)N*4);
  int*    bsum   = (int*)   alloc(1024*4);
  int*    col    = (int*)   alloc((size_t)E*4);
  float*  wsrt   = (float*) alloc((size_t)E*4);
  u16*    wt     = (u16*)   alloc((size_t)6*16384*2);  // 6 transposed bf16 weights
  u16*    B1     = (u16*)   alloc((size_t)N*D*2);  // agg_score_x (bf16)
  u16*    B2     = (u16*)   alloc((size_t)N*D*2);  // agg_ones_x -> agg_ones_enc
  u16*    B3     = (u16*)   alloc((size_t)N*D*2);  // enc_t
  u16*    B5     = (u16*)   alloc((size_t)N*D*2);  // prior
  u32*    EPSB   = (u32*)   alloc((size_t)N*64*4); // bf16x2-packed eps
  const int gG32 = (N + 31) / 32;                  // MFMA tiles (32 rows)
  float*  pblk   = (float*) alloc((size_t)gG32*4);
  (void)ws_size; (void)n_in; (void)out_size;

  float* conf = ((float*)d_out) + 1;

  u16* Wt_enc = wt + 0*16384;
  u16* Wt_pr  = wt + 1*16384;
  u16* Wt_pm  = wt + 2*16384;
  u16* Wt_ps  = wt + 3*16384;
  u16* Wt_mu  = wt + 4*16384;
  u16* Wt_std = wt + 5*16384;

  const int gE  = (E + 255) / 256;
  const int gN  = (N + 255) / 256;
  const int gW  = (N * 64 + 255) / 256;

  k_eps    <<<2048, 256, 0, stream>>>(EPSB, N*64);
  k_wconv  <<<dim3(64,6), 256, 0, stream>>>(W_enc, W_pr, W_pm, W_ps, W_mu, W_std, wt);
  k_detect <<<1, 256, 0, stream>>>((const u32*)eidx, flag);
  k_norm   <<<gE, 256, 0, stream>>>(eidx, flag, src_w, dst_w, E);
  k_init   <<<gN, 256, 0, stream>>>(cnt, N);
  k_hist   <<<gE, 256, 0, stream>>>(dst_w, cnt, E);
  k_scan1  <<<gN, 256, 0, stream>>>(cnt, rp, bsum, N);
  k_scan2  <<<1, 1024, 0, stream>>>(bsum, gN);
  k_scan3  <<<gN, 256, 0, stream>>>(rp, cur, bsum, cnt, dinv_o, N, E);
  k_scatter<<<gE, 256, 0, stream>>>(src_w, dst_w, escore, cur, col, wsrt, E);
  k_deg    <<<gN, 256, 0, stream>>>(rp, wsrt, dinv_s, N);

  // agg_sx -> B1 (bf16) ; agg_ox -> B2 (bf16)
  k_agg_dual<<<gW, 256, 0, stream>>>(x, rp, col, wsrt, dinv_s, dinv_o, B1, B2, N);
  // y=0: enc_t = relu(B1@Wenc+b) -> B3 ; y=1: prior = relu(B2@Wpr+b)+temb -> B5
  k_mfma_act2<<<dim3(gG32,2), 256, 0, stream>>>(B1, Wt_enc, b_enc, B2, Wt_pr, b_pr,
                                                temb, t_ptr, B3, B5, N);
  // agg_oe = A_ones enc_t -> B2 (bf16 gather)
  k_agg_one<<<gW, 256, 0, stream>>>(B3, rp, col, dinv_o, B2, N);
  // pm/ps/em/es + conf + kl partials, fused
  k_mfma_quad<<<gG32, 256, 0, stream>>>(B5, B2, Wt_pm, b_pm, Wt_ps, b_ps,
                                        Wt_mu, b_mu, Wt_std, b_std, EPSB,
                                        conf, pblk, N);
  k_finish<<<1, 256, 0, stream>>>(pblk, gG32, (float*)d_out, N);
}